// Round 13
// baseline (206.950 us; speedup 1.0000x reference)
//
#include <hip/hip_runtime.h>

// ---------------------------------------------------------------------------
// TransformerDecoderBlockV2: bf16 MFMA implementation for gfx950
// B=1, N=2048, M=2048, D=1024, H=16, dh=64, DFF=4096
// ---------------------------------------------------------------------------

using bf16x8 = __attribute__((ext_vector_type(8))) short;
using f32x4  = __attribute__((ext_vector_type(4))) float;

__device__ __forceinline__ ushort f2bf(float f) {
    unsigned u = __float_as_uint(f);
    unsigned r = (u + 0x7fffu + ((u >> 16) & 1u)) >> 16;
    return (ushort)r;
}

__device__ __forceinline__ float bf2f(ushort u) {
    return __uint_as_float((uint)u << 16);
}

__device__ __forceinline__ void gload16(const void* g, void* l) {
    __builtin_amdgcn_global_load_lds(
        (const __attribute__((address_space(1))) void*)g,
        (__attribute__((address_space(3))) void*)l, 16, 0, 0);
}

__device__ __forceinline__ float gelu_erf(float v) {
    return 0.5f * v * (1.0f + erff(v * 0.70710678118654752f));
}

__device__ __forceinline__ uint cvtpk(float a, float b) {
    uint r;
    asm("v_cvt_pk_bf16_f32 %0, %1, %2" : "=v"(r) : "v"(a), "v"(b));
    return r;
}

// ---------------------------------------------------------------------------
// Fused prep: blocks 0..4095 convert x/ctx; 4096..16383 transpose+cvt the 5
// weights. Transpose path VECTORIZED: float4 loads, cvt_pk + uint2 stores.
// ---------------------------------------------------------------------------
__global__ __launch_bounds__(256) void prep_all(
    const float* __restrict__ x, const float* __restrict__ ctx,
    ushort* __restrict__ XCb,
    const float* __restrict__ Wq, const float* __restrict__ Wkv,
    const float* __restrict__ Wo, const float* __restrict__ W1,
    const float* __restrict__ W2,
    ushort* __restrict__ WqT, ushort* __restrict__ WkvT,
    ushort* __restrict__ WoT, ushort* __restrict__ W1T,
    ushort* __restrict__ W2T) {
    __shared__ float tile[32][33];
    int b = blockIdx.x;
    const int t = threadIdx.x;
    if (b < 4096) {
        const float* in = (b < 2048) ? x : ctx;
        ushort* out = XCb + ((b < 2048) ? 0 : (size_t)2048 * 1024);
        const int i = ((b & 2047) * 256 + t) * 4;
        float4 v = *(const float4*)(in + i);
        ushort4 o;
        o.x = f2bf(v.x); o.y = f2bf(v.y); o.z = f2bf(v.z); o.w = f2bf(v.w);
        *(ushort4*)(out + i) = o;
        return;
    }
    b -= 4096;
    const float* in; ushort* out; int R, C, loc;
    if (b < 1024)      { in = Wq;  out = WqT;  R = 1024; C = 1024; loc = b; }
    else if (b < 3072) { in = Wkv; out = WkvT; R = 1024; C = 2048; loc = b - 1024; }
    else if (b < 4096) { in = Wo;  out = WoT;  R = 1024; C = 1024; loc = b - 3072; }
    else if (b < 8192) { in = W1;  out = W1T;  R = 1024; C = 4096; loc = b - 4096; }
    else               { in = W2;  out = W2T;  R = 4096; C = 1024; loc = b - 8192; }
    const int nbx = C >> 5;
    const int c0 = (loc % nbx) * 32, r0 = (loc / nbx) * 32;
    // load: thread t -> row r = t>>3, cols c4..c4+3 (float4)
    {
        const int r = t >> 3, c4 = (t & 7) * 4;
        float4 v = *(const float4*)(in + (size_t)(r0 + r) * C + c0 + c4);
        tile[r][c4] = v.x; tile[r][c4 + 1] = v.y;
        tile[r][c4 + 2] = v.z; tile[r][c4 + 3] = v.w;
    }
    __syncthreads();
    // store: thread t -> out col c = t>>3, rows r4..r4+3 (uint2 = 4 bf16)
    {
        const int c = t >> 3, r4 = (t & 7) * 4;
        uint2 pk;
        pk.x = cvtpk(tile[r4][c], tile[r4 + 1][c]);
        pk.y = cvtpk(tile[r4 + 2][c], tile[r4 + 3][c]);
        *(uint2*)(out + (size_t)(c0 + c) * R + r0 + r4) = pk;
    }
}

// ---------------------------------------------------------------------------
// GEMM: C[M][N] = epilogue( A[M][K] * Bt[N][K]^T + bias ), bf16 in.
// 128x128 m97-class; SPLITK via blockIdx.z (f32 or bf16 partials).
// ---------------------------------------------------------------------------
template <int BM, int BN, int ACT, int OUTF32, int RES, int SCALED, int SPLITK>
__global__ __launch_bounds__(256) void gemm_bt(
    const ushort* __restrict__ A, int lda, const ushort* __restrict__ Bt, int ldb,
    const float* __restrict__ bias, const float* __restrict__ resid,
    void* __restrict__ Cout, int M, int N, int K, float scale) {
    constexpr int MR = BM / 32, NR = BN / 32;
    __shared__ __align__(16) ushort Asm[BM * 64];
    __shared__ __align__(16) ushort Bsm[BN * 64];
    const int tid = threadIdx.x;
    const int w = tid >> 6, lane = tid & 63, g = lane >> 4, i15 = lane & 15;
    const int wm = w >> 1, wn = w & 1;
    const int m0 = blockIdx.y * BM, n0 = blockIdx.x * BN;
    if (SPLITK) {
        A += (size_t)blockIdx.z * K;
        Bt += (size_t)blockIdx.z * K;
    }

    f32x4 acc[MR][NR] = {};

    for (int kt = 0; kt < K; kt += 64) {
#pragma unroll
        for (int q = 0; q < BM / 32; ++q) {
            int off = (w * (BM / 32) + q) * 1024 + lane * 16;
            int r = off >> 7, cb = off & 127;
            int scb = cb ^ ((r & 7) << 4);
            const void* src = (const char*)A + ((size_t)(m0 + r) * lda + kt) * 2 + scb;
            gload16(src, (char*)Asm + (w * (BM / 32) + q) * 1024);
        }
#pragma unroll
        for (int q = 0; q < BN / 32; ++q) {
            int off = (w * (BN / 32) + q) * 1024 + lane * 16;
            int r = off >> 7, cb = off & 127;
            int scb = cb ^ ((r & 7) << 4);
            const void* src = (const char*)Bt + ((size_t)(n0 + r) * ldb + kt) * 2 + scb;
            gload16(src, (char*)Bsm + (w * (BN / 32) + q) * 1024);
        }
        __syncthreads();

#pragma unroll
        for (int kc = 0; kc < 2; ++kc) {
            bf16x8 af[MR], bfr[NR];
#pragma unroll
            for (int mi = 0; mi < MR; ++mi) {
                int r = wm * (BM / 2) + mi * 16 + i15;
                af[mi] = *(const bf16x8*)((const char*)Asm + r * 128 +
                                          ((kc * 64 + g * 16) ^ ((r & 7) << 4)));
            }
#pragma unroll
            for (int ni = 0; ni < NR; ++ni) {
                int r = wn * (BN / 2) + ni * 16 + i15;
                bfr[ni] = *(const bf16x8*)((const char*)Bsm + r * 128 +
                                           ((kc * 64 + g * 16) ^ ((r & 7) << 4)));
            }
#pragma unroll
            for (int mi = 0; mi < MR; ++mi)
#pragma unroll
                for (int ni = 0; ni < NR; ++ni)
                    acc[mi][ni] = __builtin_amdgcn_mfma_f32_16x16x32_bf16(
                        af[mi], bfr[ni], acc[mi][ni], 0, 0, 0);
        }
        __syncthreads();
    }

    float* Cf = (float*)Cout;
    ushort* Cb = (ushort*)Cout;
    if (SPLITK) {
        Cf += (size_t)blockIdx.z * M * N;
        Cb += (size_t)blockIdx.z * M * N;
    }

#pragma unroll
    for (int ni = 0; ni < NR; ++ni) {
        int col = n0 + wn * (BN / 2) + ni * 16 + i15;
        float bb = bias ? bias[col] : 0.f;
#pragma unroll
        for (int mi = 0; mi < MR; ++mi) {
#pragma unroll
            for (int r2 = 0; r2 < 4; ++r2) {
                int row = m0 + wm * (BM / 2) + mi * 16 + 4 * g + r2;
                float v = acc[mi][ni][r2] + bb;
                if (ACT) v = gelu_erf(v);
                if (SCALED) v *= scale;
                size_t off = (size_t)row * N + col;
                if (OUTF32) {
                    float rv = RES ? resid[off] : 0.f;
                    Cf[off] = v + rv;
                } else {
                    Cb[off] = f2bf(v);
                }
            }
        }
    }
}

// ---------------------------------------------------------------------------
// Fused QKV projection: C = [x;ctx] @ [Wq|Wkv] over concatenated WqkvT
// [3072][1024]. 640 blocks: bid<128 -> Q tiles (cols 0..1023, rows<2048,
// scaled+bq -> Qs); else K tiles (cols 1024..2047 -> Kb) / V tiles
// (cols 2048..3071 -> Vt TRANSPOSED).  128x128 m97 structure.
// ---------------------------------------------------------------------------
__global__ __launch_bounds__(256) void gemm_qkv(
    const ushort* __restrict__ A,      // XCb [4096][1024]
    const ushort* __restrict__ Bt,     // WqkvT [3072][1024]
    const float* __restrict__ bq, const float* __restrict__ bkv,
    ushort* __restrict__ Qs, ushort* __restrict__ Kb, ushort* __restrict__ Vt,
    float qscale) {
    constexpr int MR = 4, NR = 4;
    __shared__ __align__(16) ushort Asm[128 * 64];
    __shared__ __align__(16) ushort Bsm[128 * 64];
    const int tid = threadIdx.x;
    const int w = tid >> 6, lane = tid & 63, g = lane >> 4, i15 = lane & 15;
    const int wm = w >> 1, wn = w & 1;
    const int bid = blockIdx.x;
    int bx, by;
    if (bid < 128) { bx = bid & 7; by = bid >> 3; }            // Q region
    else { int b2 = bid - 128; bx = 8 + (b2 & 15); by = b2 >> 4; } // K/V region
    const int m0 = by * 128, n0 = bx * 128;
    const int reg = (n0 < 1024) ? 0 : (n0 < 2048 ? 1 : 2);

    f32x4 acc[MR][NR] = {};

    for (int kt = 0; kt < 1024; kt += 64) {
#pragma unroll
        for (int q = 0; q < 4; ++q) {
            int off = (w * 4 + q) * 1024 + lane * 16;
            int r = off >> 7, cb = off & 127;
            int scb = cb ^ ((r & 7) << 4);
            const void* src = (const char*)A + ((size_t)(m0 + r) * 1024 + kt) * 2 + scb;
            gload16(src, (char*)Asm + (w * 4 + q) * 1024);
        }
#pragma unroll
        for (int q = 0; q < 4; ++q) {
            int off = (w * 4 + q) * 1024 + lane * 16;
            int r = off >> 7, cb = off & 127;
            int scb = cb ^ ((r & 7) << 4);
            const void* src = (const char*)Bt + ((size_t)(n0 + r) * 1024 + kt) * 2 + scb;
            gload16(src, (char*)Bsm + (w * 4 + q) * 1024);
        }
        __syncthreads();

#pragma unroll
        for (int kc = 0; kc < 2; ++kc) {
            bf16x8 af[MR], bfr[NR];
#pragma unroll
            for (int mi = 0; mi < MR; ++mi) {
                int r = wm * 64 + mi * 16 + i15;
                af[mi] = *(const bf16x8*)((const char*)Asm + r * 128 +
                                          ((kc * 64 + g * 16) ^ ((r & 7) << 4)));
            }
#pragma unroll
            for (int ni = 0; ni < NR; ++ni) {
                int r = wn * 64 + ni * 16 + i15;
                bfr[ni] = *(const bf16x8*)((const char*)Bsm + r * 128 +
                                           ((kc * 64 + g * 16) ^ ((r & 7) << 4)));
            }
#pragma unroll
            for (int mi = 0; mi < MR; ++mi)
#pragma unroll
                for (int ni = 0; ni < NR; ++ni)
                    acc[mi][ni] = __builtin_amdgcn_mfma_f32_16x16x32_bf16(
                        af[mi], bfr[ni], acc[mi][ni], 0, 0, 0);
        }
        __syncthreads();
    }

#pragma unroll
    for (int ni = 0; ni < NR; ++ni) {
        int col = n0 + wn * 64 + ni * 16 + i15;
        float bb = (reg == 0) ? bq[col] : bkv[col - 1024];
#pragma unroll
        for (int mi = 0; mi < MR; ++mi) {
            if (reg == 2) {
                // V^T: rows 4g..4g+3 consecutive -> 8B store
                int row = m0 + wm * 64 + mi * 16 + 4 * g;
                ushort4 ov;
                ov.x = f2bf(acc[mi][ni][0] + bb);
                ov.y = f2bf(acc[mi][ni][1] + bb);
                ov.z = f2bf(acc[mi][ni][2] + bb);
                ov.w = f2bf(acc[mi][ni][3] + bb);
                *(ushort4*)(Vt + (size_t)(col - 2048) * 4096 + row) = ov;
            } else {
#pragma unroll
                for (int r2 = 0; r2 < 4; ++r2) {
                    int row = m0 + wm * 64 + mi * 16 + 4 * g + r2;
                    float v = acc[mi][ni][r2] + bb;
                    if (reg == 0) {
                        Qs[(size_t)row * 1024 + col] = f2bf(v * qscale);
                    } else {
                        Kb[(size_t)row * 1024 + (col - 1024)] = f2bf(v);
                    }
                }
            }
        }
    }
}

// ---------------------------------------------------------------------------
// Flash attention v7: 8 waves x 16 q-rows, reg-staged dbuf K/V LDS,
// 16x16 swapped QK^T, exp2, defer-max, setprio, bf16 split partials.
// l computed by MFMA ones-column trick (ls accumulator, rows 4g+r).
// ---------------------------------------------------------------------------
template <int NS>
__global__ __launch_bounds__(512) void flash_attn(
    const ushort* __restrict__ Q,    // [2048][1024] bf16 (pre-scaled 0.125*log2e)
    const ushort* __restrict__ Kb,   // [4096][1024] bf16
    const ushort* __restrict__ Vt,   // [1024][4096] bf16
    ushort* __restrict__ O,          // NS==1: [2048][1024] bf16
    ushort* __restrict__ Opart,      // NS>1: [NS][2048][1024] bf16 (unnormalized)
    float* __restrict__ Ml) {        // NS>1: [NS][2048][16][2] f32
    constexpr int D = 1024;
    __shared__ __align__(16) ushort Ksm[2][64 * 64];
    __shared__ __align__(16) ushort Vsm[2][64 * 64];
    __shared__ __align__(16) ushort Psm[8][16 * 64];

    const int tid = threadIdx.x;
    const int w = tid >> 6, lane = tid & 63, g = lane >> 4, i15 = lane & 15;
    const int bid = blockIdx.x;
    const int h = bid & 15;                 // bid%8 == h%8 -> same-head same-XCD
    const int qB = 15 - ((bid >> 4) & 15);  // heavy q-blocks first
    const int s = (NS > 1) ? (bid >> 8) : 0;
    const int qb = qB * 128 + w * 16;       // wave's first q-row
    const int qrow = qb + i15;
    const int diagW = qb >> 6;              // wave's partial-mask tile
    const int diagB = 2 * qB + 1;           // block's last self tile
    const int nt = diagB + 33;
    const int lo = (s * nt) / NS;
    const int hi = ((s + 1) * nt) / NS;

    bf16x8 qf[2];
    qf[0] = *(const bf16x8*)(Q + (size_t)qrow * D + h * 64 + g * 8);
    qf[1] = *(const bf16x8*)(Q + (size_t)qrow * D + h * 64 + 32 + g * 8);

    const short oneb = (short)0x3F80;       // 1.0 bf16
    const bf16x8 ones = {oneb, oneb, oneb, oneb, oneb, oneb, oneb, oneb};

    f32x4 o[4] = {};
    f32x4 ls = {};                          // row-sums l, rows 4g+r (replicated)
    float m_run = -INFINITY;

    const int sr  = tid >> 3;               // 0..63
    const int scb = (tid & 7) * 16;
    const int ssw = scb ^ ((sr & 7) << 4);
    const char* kb0 = (const char*)Kb + ((size_t)sr * 1024 + h * 64) * 2 + scb;
    const char* vb0 = (const char*)Vt + ((size_t)(h * 64 + sr) * 4096) * 2 + scb;

    uint4 kreg, vreg;
    auto jt_of = [&](int t) { return (t <= diagB) ? t : (32 + (t - diagB - 1)); };
    auto stage = [&](int t) {
        const int jt = jt_of(t);
        kreg = *(const uint4*)(kb0 + (size_t)jt * 64 * 2048);
        vreg = *(const uint4*)(vb0 + (size_t)jt * 128);
    };
    auto wlds = [&](int buf) {
        *(uint4*)((char*)Ksm[buf] + sr * 128 + ssw) = kreg;
        *(uint4*)((char*)Vsm[buf] + sr * 128 + ssw) = vreg;
    };

    const int pbase = i15 * 128;            // within Psm[w]
    const int psw = (i15 & 7) << 4;

    auto body = [&](int buf, int t) {
        const int jt = jt_of(t);
        f32x4 st[4];
        __builtin_amdgcn_s_setprio(1);
#pragma unroll
        for (int jg = 0; jg < 4; ++jg) {
            int jr = jg * 16 + i15;
            bf16x8 ka0 = *(const bf16x8*)((const char*)Ksm[buf] + jr * 128 +
                                          ((g * 16) ^ ((jr & 7) << 4)));
            bf16x8 ka1 = *(const bf16x8*)((const char*)Ksm[buf] + jr * 128 +
                                          ((64 + g * 16) ^ ((jr & 7) << 4)));
            f32x4 z = {};
            z = __builtin_amdgcn_mfma_f32_16x16x32_bf16(ka0, qf[0], z, 0, 0, 0);
            z = __builtin_amdgcn_mfma_f32_16x16x32_bf16(ka1, qf[1], z, 0, 0, 0);
            st[jg] = z;
        }
        __builtin_amdgcn_s_setprio(0);
        if (jt >= diagW && jt <= diagB) {
#pragma unroll
            for (int jg = 0; jg < 4; ++jg)
#pragma unroll
                for (int r = 0; r < 4; ++r) {
                    int j = jt * 64 + jg * 16 + 4 * g + r;
                    if (j > qrow) st[jg][r] = -50000.f;
                }
        }

        // row max: max3-shaped tree + 2 swizzles
        float a0 = fmaxf(fmaxf(st[0][0], st[0][1]), st[0][2]);
        float a1 = fmaxf(fmaxf(st[0][3], st[1][0]), st[1][1]);
        float a2 = fmaxf(fmaxf(st[1][2], st[1][3]), st[2][0]);
        float a3 = fmaxf(fmaxf(st[2][1], st[2][2]), st[2][3]);
        float a4 = fmaxf(fmaxf(st[3][0], st[3][1]), st[3][2]);
        float b0 = fmaxf(fmaxf(a0, a1), a2);
        float b1 = fmaxf(fmaxf(a3, a4), st[3][3]);
        float mt = fmaxf(b0, b1);
        mt = fmaxf(mt, __shfl_xor(mt, 16));
        mt = fmaxf(mt, __shfl_xor(mt, 32));

        const bool skip = __all(mt - m_run <= 8.f);
        float mnew, fscale;
        if (skip) { mnew = m_run; fscale = 1.f; }
        else      { mnew = fmaxf(m_run, mt); fscale = exp2f(m_run - mnew); }

        float pf[4][4];
#pragma unroll
        for (int jg = 0; jg < 4; ++jg)
#pragma unroll
            for (int r = 0; r < 4; ++r) pf[jg][r] = exp2f(st[jg][r] - mnew);
        m_run = mnew;

        if (!skip) {
#pragma unroll
            for (int r = 0; r < 4; ++r) {
                float fr = __shfl(fscale, 20 * g + r);
#pragma unroll
                for (int dg = 0; dg < 4; ++dg) o[dg][r] *= fr;
                ls[r] *= fr;
            }
        }

#pragma unroll
        for (int jg = 0; jg < 4; ++jg) {
            uint2 pk;
            pk.x = cvtpk(pf[jg][0], pf[jg][1]);
            pk.y = cvtpk(pf[jg][2], pf[jg][3]);
            *(uint2*)((char*)Psm[w] + pbase + ((jg * 32 + g * 8) ^ psw)) = pk;
        }

        __builtin_amdgcn_s_setprio(1);
#pragma unroll
        for (int jc = 0; jc < 2; ++jc) {
            bf16x8 pa = *(const bf16x8*)((const char*)Psm[w] + pbase +
                                         ((jc * 64 + g * 16) ^ psw));
            ls = __builtin_amdgcn_mfma_f32_16x16x32_bf16(pa, ones, ls, 0, 0, 0);
#pragma unroll
            for (int dg = 0; dg < 4; ++dg) {
                int dr = dg * 16 + i15;
                bf16x8 vb = *(const bf16x8*)((const char*)Vsm[buf] + dr * 128 +
                                             ((jc * 64 + g * 16) ^ ((dr & 7) << 4)));
                o[dg] = __builtin_amdgcn_mfma_f32_16x16x32_bf16(pa, vb, o[dg], 0, 0, 0);
            }
        }
        __builtin_amdgcn_s_setprio(0);
    };

    stage(lo);
    wlds(0);
    __syncthreads();

    int t = lo;
    for (; t + 1 < hi; t += 2) {
        stage(t + 1);
        body(0, t);
        wlds(1);
        __syncthreads();
        if (t + 2 < hi) stage(t + 2);
        body(1, t + 1);
        if (t + 2 < hi) { wlds(0); __syncthreads(); }
    }
    if (t < hi) body(0, t);

    if (NS > 1) {
#pragma unroll
        for (int r = 0; r < 4; ++r) {
            if (i15 == 4 * g + r) {
                float* mp = Ml + ((size_t)(s * 2048 + qrow) * 16 + h) * 2;
                mp[0] = m_run; mp[1] = ls[r];
            }
        }
#pragma unroll
        for (int r = 0; r < 4; ++r)
#pragma unroll
            for (int dg = 0; dg < 4; ++dg) {
                int row = qb + 4 * g + r;
                int col = h * 64 + dg * 16 + i15;
                Opart[(size_t)(s * 2048 + row) * 1024 + col] = f2bf(o[dg][r]);
            }
    } else {
#pragma unroll
        for (int r = 0; r < 4; ++r) {
            float inv = 1.f / ls[r];
#pragma unroll
            for (int dg = 0; dg < 4; ++dg) {
                int row = qb + 4 * g + r;
                int col = h * 64 + dg * 16 + i15;
                O[(size_t)row * D + col] = f2bf(o[dg][r] * inv);
            }
        }
    }
}

// ---------------------------------------------------------------------------
template <int NS>
__global__ __launch_bounds__(256) void attn_combine(
    const ushort* __restrict__ Opart, const float* __restrict__ Ml,
    ushort* __restrict__ O) {
    const int row = blockIdx.x, tid = threadIdx.x;
    const int c = tid * 4, h = c >> 6;
    float ms[NS], lsv[NS];
#pragma unroll
    for (int s = 0; s < NS; ++s) {
        const float* mp = Ml + ((size_t)(s * 2048 + row) * 16 + h) * 2;
        ms[s] = mp[0]; lsv[s] = mp[1];
    }
    float m = ms[0];
#pragma unroll
    for (int s = 1; s < NS; ++s) m = fmaxf(m, ms[s]);
    float denom = 0.f, wgt[NS];
#pragma unroll
    for (int s = 0; s < NS; ++s) { wgt[s] = exp2f(ms[s] - m); denom += lsv[s] * wgt[s]; }
    const float inv = 1.f / denom;
    float ax = 0, ay = 0, az = 0, aw = 0;
#pragma unroll
    for (int s = 0; s < NS; ++s) {
        ushort4 a = *(const ushort4*)(Opart + (size_t)(s * 2048 + row) * 1024 + c);
        ax += bf2f(a.x) * wgt[s]; ay += bf2f(a.y) * wgt[s];
        az += bf2f(a.z) * wgt[s]; aw += bf2f(a.w) * wgt[s];
    }
    ushort4 ob;
    ob.x = f2bf(ax * inv); ob.y = f2bf(ay * inv);
    ob.z = f2bf(az * inv); ob.w = f2bf(aw * inv);
    *(ushort4*)(O + (size_t)row * 1024 + c) = ob;
}

// ---------------------------------------------------------------------------
__global__ __launch_bounds__(256) void layernorm_k(
    const float* __restrict__ in, const float* __restrict__ gam,
    const float* __restrict__ bet, float* __restrict__ outf,
    ushort* __restrict__ outb) {
    const int row = blockIdx.x, tid = threadIdx.x;
    const float4 v = *(const float4*)(in + (size_t)row * 1024 + tid * 4);
    float s = v.x + v.y + v.z + v.w;
    float sq = v.x * v.x + v.y * v.y + v.z * v.z + v.w * v.w;
#pragma unroll
    for (int d = 1; d < 64; d <<= 1) {
        s += __shfl_xor(s, d);
        sq += __shfl_xor(sq, d);
    }
    __shared__ float red[8];
    const int w = tid >> 6;
    if ((tid & 63) == 0) { red[w] = s; red[4 + w] = sq; }
    __syncthreads();
    s = red[0] + red[1] + red[2] + red[3];
    sq = red[4] + red[5] + red[6] + red[7];
    const float mu = s * (1.f / 1024.f);
    const float rs = rsqrtf(sq * (1.f / 1024.f) - mu * mu + 1e-5f);
    const float4 gg = *(const float4*)(gam + tid * 4);
    const float4 bb = *(const float4*)(bet + tid * 4);
    float4 o;
    o.x = (v.x - mu) * rs * gg.x + bb.x;
    o.y = (v.y - mu) * rs * gg.y + bb.y;
    o.z = (v.z - mu) * rs * gg.z + bb.z;
    o.w = (v.w - mu) * rs * gg.w + bb.w;
    *(float4*)(outf + (size_t)row * 1024 + tid * 4) = o;
    if (outb) {
        ushort4 ob;
        ob.x = f2bf(o.x); ob.y = f2bf(o.y); ob.z = f2bf(o.z); ob.w = f2bf(o.w);
        *(ushort4*)(outb + (size_t)row * 1024 + tid * 4) = ob;
    }
}

// ---------------------------------------------------------------------------
// LN over (sum of NP split-K partials + bias + resid); partials f32 or bf16.
// ---------------------------------------------------------------------------
template <int NP, int PBF16, int OUTB>
__global__ __launch_bounds__(256) void layernorm_comb(
    const void* __restrict__ P,
    const float* __restrict__ bias, const float* __restrict__ resid,
    const float* __restrict__ gam, const float* __restrict__ bet,
    float* __restrict__ outf, ushort* __restrict__ outb) {
    const int row = blockIdx.x, tid = threadIdx.x;
    const float4 rr = *(const float4*)(resid + (size_t)row * 1024 + tid * 4);
    const float4 bs = *(const float4*)(bias + tid * 4);
    float4 v;
    v.x = rr.x + bs.x; v.y = rr.y + bs.y; v.z = rr.z + bs.z; v.w = rr.w + bs.w;
#pragma unroll
    for (int p = 0; p < NP; ++p) {
        if (PBF16) {
            ushort4 a = *(const ushort4*)((const ushort*)P +
                          (size_t)(p * 2048 + row) * 1024 + tid * 4);
            v.x += bf2f(a.x); v.y += bf2f(a.y); v.z += bf2f(a.z); v.w += bf2f(a.w);
        } else {
            float4 a = *(const float4*)((const float*)P +
                          (size_t)(p * 2048 + row) * 1024 + tid * 4);
            v.x += a.x; v.y += a.y; v.z += a.z; v.w += a.w;
        }
    }
    float s = v.x + v.y + v.z + v.w;
    float sq = v.x * v.x + v.y * v.y + v.z * v.z + v.w * v.w;
#pragma unroll
    for (int d = 1; d < 64; d <<= 1) {
        s += __shfl_xor(s, d);
        sq += __shfl_xor(sq, d);
    }
    __shared__ float red[8];
    const int w = tid >> 6;
    if ((tid & 63) == 0) { red[w] = s; red[4 + w] = sq; }
    __syncthreads();
    s = red[0] + red[1] + red[2] + red[3];
    sq = red[4] + red[5] + red[6] + red[7];
    const float mu = s * (1.f / 1024.f);
    const float rs = rsqrtf(sq * (1.f / 1024.f) - mu * mu + 1e-5f);
    const float4 gg = *(const float4*)(gam + tid * 4);
    const float4 bb = *(const float4*)(bet + tid * 4);
    float4 o;
    o.x = (v.x - mu) * rs * gg.x + bb.x;
    o.y = (v.y - mu) * rs * gg.y + bb.y;
    o.z = (v.z - mu) * rs * gg.z + bb.z;
    o.w = (v.w - mu) * rs * gg.w + bb.w;
    *(float4*)(outf + (size_t)row * 1024 + tid * 4) = o;
    if (OUTB) {
        ushort4 ob;
        ob.x = f2bf(o.x); ob.y = f2bf(o.y); ob.z = f2bf(o.z); ob.w = f2bf(o.w);
        *(ushort4*)(outb + (size_t)row * 1024 + tid * 4) = ob;
    }
}

// ---------------------------------------------------------------------------
extern "C" void kernel_launch(void* const* d_in, const int* in_sizes, int n_in,
                              void* d_out, int out_size, void* d_ws, size_t ws_size,
                              hipStream_t stream) {
    const float* x    = (const float*)d_in[0];
    const float* ctx  = (const float*)d_in[1];
    const float* Wq   = (const float*)d_in[2];
    const float* bq   = (const float*)d_in[3];
    const float* Wkv  = (const float*)d_in[4];
    const float* bkv  = (const float*)d_in[5];
    const float* Wo   = (const float*)d_in[6];
    const float* bo   = (const float*)d_in[7];
    const float* g1   = (const float*)d_in[8];
    const float* b1   = (const float*)d_in[9];
    const float* W1   = (const float*)d_in[10];
    const float* bf1  = (const float*)d_in[11];
    const float* W2   = (const float*)d_in[12];
    const float* bf2  = (const float*)d_in[13];
    const float* g2   = (const float*)d_in[14];
    const float* b2   = (const float*)d_in[15];

    char* ws = (char*)d_ws;
    const size_t MB = 1u << 20;
    ushort* XCb  = (ushort*)(ws + 0);        // 8MB; dead after QKV gemm
    ushort* WoT  = (ushort*)(ws + 8 * MB);   // 2MB
    ushort* W1T  = (ushort*)(ws + 10 * MB);  // 8MB
    ushort* W2T  = (ushort*)(ws + 18 * MB);  // 8MB
    ushort* WqT  = (ushort*)(ws + 26 * MB);  // 2MB; contiguous with WkvT
    ushort* WkvT = (ushort*)(ws + 28 * MB);  // 4MB; WqT+WkvT = WqkvT [3072][1024]
    ushort* Qs   = (ushort*)(ws + 32 * MB);  // 4MB; later x1f
    ushort* attn = (ushort*)(ws + 36 * MB);  // 4MB
    ushort* Kb   = (ushort*)(ws + 40 * MB);  // 8MB; later ffb (part)
    ushort* Vt   = (ushort*)(ws + 48 * MB);  // 8MB; later ffb (part)
    ushort* x1b  = (ushort*)(ws + 26 * MB);  // 4MB (over WqT+WkvT after use)
    float*  x1f  = (float*)(ws + 32 * MB);   // 8MB (over Qs+attn after use)
    ushort* ffb  = (ushort*)(ws + 40 * MB);  // 16MB (over Kb+Vt)
    float*  y1   = (float*)(ws + 56 * MB);   // 8MB (fallback path)
    ushort* Opart = (ushort*)(ws + 64 * MB); // 16MB bf16 attn partials (NS=4)
    float*  Pwo   = (float*)(ws + 64 * MB);  // 16MB Wo split-2 f32 partials
    ushort* Pk4b  = (ushort*)(ws + 64 * MB); // 16MB FFN2 split-4 bf16 partials
    float*  Pk2   = (float*)(ws + 0);        // 16MB FFN2 split-2 fallback
    float*  Ml    = (float*)(ws + 80 * MB);  // 1MB

    prep_all<<<16384, 256, 0, stream>>>(x, ctx, XCb, Wq, Wkv, Wo, W1, W2,
                                        WqT, WkvT, WoT, W1T, W2T);
    // Fused QKV projection (WqT|WkvT contiguous = WqkvT [3072][1024])
    gemm_qkv<<<640, 256, 0, stream>>>(XCb, WqT, bq, bkv, Qs, Kb, Vt,
                                      0.18033688011112042f);

    const bool big = ws_size >= 82 * MB;
    if (big) {
        flash_attn<4><<<1024, 512, 0, stream>>>(Qs, Kb, Vt, nullptr, Opart, Ml);
        attn_combine<4><<<2048, 256, 0, stream>>>(Opart, Ml, attn);
        // Wo split-K x2 -> raw f32 partials; combine fused into LN1
        gemm_bt<64, 128, 0, 1, 0, 0, 1><<<dim3(8, 32, 2), 256, 0, stream>>>(
            attn, 1024, WoT, 1024, nullptr, nullptr, Pwo,
            2048, 1024, 512, 1.f);
        layernorm_comb<2, 0, 1><<<2048, 256, 0, stream>>>(
            Pwo, bo, x, g1, b1, x1f, x1b);
        gemm_bt<128, 128, 1, 0, 0, 0, 0><<<dim3(32, 16), 256, 0, stream>>>(
            x1b, 1024, W1T, 1024, bf1, nullptr, ffb,
            2048, 4096, 1024, 1.f);
        // FFN2 split-K x4, bf16 partials, merged in final LN
        gemm_bt<128, 128, 0, 0, 0, 0, 1><<<dim3(8, 16, 4), 256, 0, stream>>>(
            ffb, 4096, W2T, 4096, nullptr, nullptr, Pk4b,
            2048, 1024, 1024, 1.f);
        layernorm_comb<4, 1, 0><<<2048, 256, 0, stream>>>(
            Pk4b, bf2, x1f, g2, b2, (float*)d_out, nullptr);
    } else {
        flash_attn<1><<<256, 512, 0, stream>>>(Qs, Kb, Vt, attn, nullptr, nullptr);
        gemm_bt<64, 128, 0, 1, 1, 0, 0><<<dim3(8, 32), 256, 0, stream>>>(
            attn, 1024, WoT, 1024, bo, x, y1, 2048, 1024, 1024, 1.f);
        layernorm_k<<<2048, 256, 0, stream>>>(y1, g1, b1, x1f, x1b);
        gemm_bt<128, 128, 1, 0, 0, 0, 0><<<dim3(32, 16), 256, 0, stream>>>(
            x1b, 1024, W1T, 1024, bf1, nullptr, ffb, 2048, 4096, 1024, 1.f);
        gemm_bt<128, 128, 0, 1, 0, 0, 1><<<dim3(8, 16, 2), 256, 0, stream>>>(
            ffb, 4096, W2T, 4096, nullptr, nullptr, Pk2, 2048, 1024, 2048, 1.f);
        layernorm_comb<2, 0, 0><<<2048, 256, 0, stream>>>(
            Pk2, bf2, x1f, g2, b2, (float*)d_out, nullptr);
    }
}

// Round 14
// 206.008 us; speedup vs baseline: 1.0046x; 1.0046x over previous
//
#include <hip/hip_runtime.h>

// ---------------------------------------------------------------------------
// TransformerDecoderBlockV2: bf16 MFMA implementation for gfx950
// B=1, N=2048, M=2048, D=1024, H=16, dh=64, DFF=4096
// ---------------------------------------------------------------------------

using bf16x8 = __attribute__((ext_vector_type(8))) short;
using f32x4  = __attribute__((ext_vector_type(4))) float;

__device__ __forceinline__ ushort f2bf(float f) {
    unsigned u = __float_as_uint(f);
    unsigned r = (u + 0x7fffu + ((u >> 16) & 1u)) >> 16;
    return (ushort)r;
}

__device__ __forceinline__ float bf2f(ushort u) {
    return __uint_as_float((uint)u << 16);
}

__device__ __forceinline__ void gload16(const void* g, void* l) {
    __builtin_amdgcn_global_load_lds(
        (const __attribute__((address_space(1))) void*)g,
        (__attribute__((address_space(3))) void*)l, 16, 0, 0);
}

__device__ __forceinline__ float gelu_erf(float v) {
    return 0.5f * v * (1.0f + erff(v * 0.70710678118654752f));
}

__device__ __forceinline__ uint cvtpk(float a, float b) {
    uint r;
    asm("v_cvt_pk_bf16_f32 %0, %1, %2" : "=v"(r) : "v"(a), "v"(b));
    return r;
}

// ---------------------------------------------------------------------------
// Fused prep: blocks 0..4095 convert x/ctx; 4096..16383 transpose+cvt the 5
// weights. Transpose path vectorized: float4 loads, cvt_pk + uint2 stores.
// ---------------------------------------------------------------------------
__global__ __launch_bounds__(256) void prep_all(
    const float* __restrict__ x, const float* __restrict__ ctx,
    ushort* __restrict__ XCb,
    const float* __restrict__ Wq, const float* __restrict__ Wkv,
    const float* __restrict__ Wo, const float* __restrict__ W1,
    const float* __restrict__ W2,
    ushort* __restrict__ WqT, ushort* __restrict__ WkvT,
    ushort* __restrict__ WoT, ushort* __restrict__ W1T,
    ushort* __restrict__ W2T) {
    __shared__ float tile[32][33];
    int b = blockIdx.x;
    const int t = threadIdx.x;
    if (b < 4096) {
        const float* in = (b < 2048) ? x : ctx;
        ushort* out = XCb + ((b < 2048) ? 0 : (size_t)2048 * 1024);
        const int i = ((b & 2047) * 256 + t) * 4;
        float4 v = *(const float4*)(in + i);
        ushort4 o;
        o.x = f2bf(v.x); o.y = f2bf(v.y); o.z = f2bf(v.z); o.w = f2bf(v.w);
        *(ushort4*)(out + i) = o;
        return;
    }
    b -= 4096;
    const float* in; ushort* out; int R, C, loc;
    if (b < 1024)      { in = Wq;  out = WqT;  R = 1024; C = 1024; loc = b; }
    else if (b < 3072) { in = Wkv; out = WkvT; R = 1024; C = 2048; loc = b - 1024; }
    else if (b < 4096) { in = Wo;  out = WoT;  R = 1024; C = 1024; loc = b - 3072; }
    else if (b < 8192) { in = W1;  out = W1T;  R = 1024; C = 4096; loc = b - 4096; }
    else               { in = W2;  out = W2T;  R = 4096; C = 1024; loc = b - 8192; }
    const int nbx = C >> 5;
    const int c0 = (loc % nbx) * 32, r0 = (loc / nbx) * 32;
    {
        const int r = t >> 3, c4 = (t & 7) * 4;
        float4 v = *(const float4*)(in + (size_t)(r0 + r) * C + c0 + c4);
        tile[r][c4] = v.x; tile[r][c4 + 1] = v.y;
        tile[r][c4 + 2] = v.z; tile[r][c4 + 3] = v.w;
    }
    __syncthreads();
    {
        const int c = t >> 3, r4 = (t & 7) * 4;
        uint2 pk;
        pk.x = cvtpk(tile[r4][c], tile[r4 + 1][c]);
        pk.y = cvtpk(tile[r4 + 2][c], tile[r4 + 3][c]);
        *(uint2*)(out + (size_t)(c0 + c) * R + r0 + r4) = pk;
    }
}

// ---------------------------------------------------------------------------
// GEMM: C[M][N] = epilogue( A[M][K] * Bt[N][K]^T + bias ), bf16 in.
// 128x128 m97-class; SPLITK via blockIdx.z (f32 or bf16 partials).
// ---------------------------------------------------------------------------
template <int BM, int BN, int ACT, int OUTF32, int RES, int SCALED, int SPLITK>
__global__ __launch_bounds__(256) void gemm_bt(
    const ushort* __restrict__ A, int lda, const ushort* __restrict__ Bt, int ldb,
    const float* __restrict__ bias, const float* __restrict__ resid,
    void* __restrict__ Cout, int M, int N, int K, float scale) {
    constexpr int MR = BM / 32, NR = BN / 32;
    __shared__ __align__(16) ushort Asm[BM * 64];
    __shared__ __align__(16) ushort Bsm[BN * 64];
    const int tid = threadIdx.x;
    const int w = tid >> 6, lane = tid & 63, g = lane >> 4, i15 = lane & 15;
    const int wm = w >> 1, wn = w & 1;
    const int m0 = blockIdx.y * BM, n0 = blockIdx.x * BN;
    if (SPLITK) {
        A += (size_t)blockIdx.z * K;
        Bt += (size_t)blockIdx.z * K;
    }

    f32x4 acc[MR][NR] = {};

    for (int kt = 0; kt < K; kt += 64) {
#pragma unroll
        for (int q = 0; q < BM / 32; ++q) {
            int off = (w * (BM / 32) + q) * 1024 + lane * 16;
            int r = off >> 7, cb = off & 127;
            int scb = cb ^ ((r & 7) << 4);
            const void* src = (const char*)A + ((size_t)(m0 + r) * lda + kt) * 2 + scb;
            gload16(src, (char*)Asm + (w * (BM / 32) + q) * 1024);
        }
#pragma unroll
        for (int q = 0; q < BN / 32; ++q) {
            int off = (w * (BN / 32) + q) * 1024 + lane * 16;
            int r = off >> 7, cb = off & 127;
            int scb = cb ^ ((r & 7) << 4);
            const void* src = (const char*)Bt + ((size_t)(n0 + r) * ldb + kt) * 2 + scb;
            gload16(src, (char*)Bsm + (w * (BN / 32) + q) * 1024);
        }
        __syncthreads();

#pragma unroll
        for (int kc = 0; kc < 2; ++kc) {
            bf16x8 af[MR], bfr[NR];
#pragma unroll
            for (int mi = 0; mi < MR; ++mi) {
                int r = wm * (BM / 2) + mi * 16 + i15;
                af[mi] = *(const bf16x8*)((const char*)Asm + r * 128 +
                                          ((kc * 64 + g * 16) ^ ((r & 7) << 4)));
            }
#pragma unroll
            for (int ni = 0; ni < NR; ++ni) {
                int r = wn * (BN / 2) + ni * 16 + i15;
                bfr[ni] = *(const bf16x8*)((const char*)Bsm + r * 128 +
                                           ((kc * 64 + g * 16) ^ ((r & 7) << 4)));
            }
#pragma unroll
            for (int mi = 0; mi < MR; ++mi)
#pragma unroll
                for (int ni = 0; ni < NR; ++ni)
                    acc[mi][ni] = __builtin_amdgcn_mfma_f32_16x16x32_bf16(
                        af[mi], bfr[ni], acc[mi][ni], 0, 0, 0);
        }
        __syncthreads();
    }

    float* Cf = (float*)Cout;
    ushort* Cb = (ushort*)Cout;
    if (SPLITK) {
        Cf += (size_t)blockIdx.z * M * N;
        Cb += (size_t)blockIdx.z * M * N;
    }

#pragma unroll
    for (int ni = 0; ni < NR; ++ni) {
        int col = n0 + wn * (BN / 2) + ni * 16 + i15;
        float bb = bias ? bias[col] : 0.f;
#pragma unroll
        for (int mi = 0; mi < MR; ++mi) {
#pragma unroll
            for (int r2 = 0; r2 < 4; ++r2) {
                int row = m0 + wm * (BM / 2) + mi * 16 + 4 * g + r2;
                float v = acc[mi][ni][r2] + bb;
                if (ACT) v = gelu_erf(v);
                if (SCALED) v *= scale;
                size_t off = (size_t)row * N + col;
                if (OUTF32) {
                    float rv = RES ? resid[off] : 0.f;
                    Cf[off] = v + rv;
                } else {
                    Cb[off] = f2bf(v);
                }
            }
        }
    }
}

// ---------------------------------------------------------------------------
// Fused QKV projection over concatenated WqkvT [3072][1024].
// ---------------------------------------------------------------------------
__global__ __launch_bounds__(256) void gemm_qkv(
    const ushort* __restrict__ A,      // XCb [4096][1024]
    const ushort* __restrict__ Bt,     // WqkvT [3072][1024]
    const float* __restrict__ bq, const float* __restrict__ bkv,
    ushort* __restrict__ Qs, ushort* __restrict__ Kb, ushort* __restrict__ Vt,
    float qscale) {
    constexpr int MR = 4, NR = 4;
    __shared__ __align__(16) ushort Asm[128 * 64];
    __shared__ __align__(16) ushort Bsm[128 * 64];
    const int tid = threadIdx.x;
    const int w = tid >> 6, lane = tid & 63, g = lane >> 4, i15 = lane & 15;
    const int wm = w >> 1, wn = w & 1;
    const int bid = blockIdx.x;
    int bx, by;
    if (bid < 128) { bx = bid & 7; by = bid >> 3; }
    else { int b2 = bid - 128; bx = 8 + (b2 & 15); by = b2 >> 4; }
    const int m0 = by * 128, n0 = bx * 128;
    const int reg = (n0 < 1024) ? 0 : (n0 < 2048 ? 1 : 2);

    f32x4 acc[MR][NR] = {};

    for (int kt = 0; kt < 1024; kt += 64) {
#pragma unroll
        for (int q = 0; q < 4; ++q) {
            int off = (w * 4 + q) * 1024 + lane * 16;
            int r = off >> 7, cb = off & 127;
            int scb = cb ^ ((r & 7) << 4);
            const void* src = (const char*)A + ((size_t)(m0 + r) * 1024 + kt) * 2 + scb;
            gload16(src, (char*)Asm + (w * 4 + q) * 1024);
        }
#pragma unroll
        for (int q = 0; q < 4; ++q) {
            int off = (w * 4 + q) * 1024 + lane * 16;
            int r = off >> 7, cb = off & 127;
            int scb = cb ^ ((r & 7) << 4);
            const void* src = (const char*)Bt + ((size_t)(n0 + r) * 1024 + kt) * 2 + scb;
            gload16(src, (char*)Bsm + (w * 4 + q) * 1024);
        }
        __syncthreads();

#pragma unroll
        for (int kc = 0; kc < 2; ++kc) {
            bf16x8 af[MR], bfr[NR];
#pragma unroll
            for (int mi = 0; mi < MR; ++mi) {
                int r = wm * 64 + mi * 16 + i15;
                af[mi] = *(const bf16x8*)((const char*)Asm + r * 128 +
                                          ((kc * 64 + g * 16) ^ ((r & 7) << 4)));
            }
#pragma unroll
            for (int ni = 0; ni < NR; ++ni) {
                int r = wn * 64 + ni * 16 + i15;
                bfr[ni] = *(const bf16x8*)((const char*)Bsm + r * 128 +
                                           ((kc * 64 + g * 16) ^ ((r & 7) << 4)));
            }
#pragma unroll
            for (int mi = 0; mi < MR; ++mi)
#pragma unroll
                for (int ni = 0; ni < NR; ++ni)
                    acc[mi][ni] = __builtin_amdgcn_mfma_f32_16x16x32_bf16(
                        af[mi], bfr[ni], acc[mi][ni], 0, 0, 0);
        }
        __syncthreads();
    }

#pragma unroll
    for (int ni = 0; ni < NR; ++ni) {
        int col = n0 + wn * 64 + ni * 16 + i15;
        float bb = (reg == 0) ? bq[col] : bkv[col - 1024];
#pragma unroll
        for (int mi = 0; mi < MR; ++mi) {
            if (reg == 2) {
                int row = m0 + wm * 64 + mi * 16 + 4 * g;
                ushort4 ov;
                ov.x = f2bf(acc[mi][ni][0] + bb);
                ov.y = f2bf(acc[mi][ni][1] + bb);
                ov.z = f2bf(acc[mi][ni][2] + bb);
                ov.w = f2bf(acc[mi][ni][3] + bb);
                *(ushort4*)(Vt + (size_t)(col - 2048) * 4096 + row) = ov;
            } else {
#pragma unroll
                for (int r2 = 0; r2 < 4; ++r2) {
                    int row = m0 + wm * 64 + mi * 16 + 4 * g + r2;
                    float v = acc[mi][ni][r2] + bb;
                    if (reg == 0) {
                        Qs[(size_t)row * 1024 + col] = f2bf(v * qscale);
                    } else {
                        Kb[(size_t)row * 1024 + (col - 1024)] = f2bf(v);
                    }
                }
            }
        }
    }
}

// ---------------------------------------------------------------------------
// Flash attention v7: 8 waves x 16 q-rows, reg-staged dbuf K/V LDS,
// 16x16 swapped QK^T, exp2, defer-max, setprio, bf16 split partials.
// l computed by MFMA ones-column trick (ls accumulator, rows 4g+r).
// ---------------------------------------------------------------------------
template <int NS>
__global__ __launch_bounds__(512) void flash_attn(
    const ushort* __restrict__ Q,    // [2048][1024] bf16 (pre-scaled 0.125*log2e)
    const ushort* __restrict__ Kb,   // [4096][1024] bf16
    const ushort* __restrict__ Vt,   // [1024][4096] bf16
    ushort* __restrict__ O,          // NS==1: [2048][1024] bf16
    ushort* __restrict__ Opart,      // NS>1: [NS][2048][1024] bf16 (unnormalized)
    float* __restrict__ Ml) {        // NS>1: [NS][2048][16][2] f32
    constexpr int D = 1024;
    __shared__ __align__(16) ushort Ksm[2][64 * 64];
    __shared__ __align__(16) ushort Vsm[2][64 * 64];
    __shared__ __align__(16) ushort Psm[8][16 * 64];

    const int tid = threadIdx.x;
    const int w = tid >> 6, lane = tid & 63, g = lane >> 4, i15 = lane & 15;
    const int bid = blockIdx.x;
    const int h = bid & 15;
    const int qB = 15 - ((bid >> 4) & 15);
    const int s = (NS > 1) ? (bid >> 8) : 0;
    const int qb = qB * 128 + w * 16;
    const int qrow = qb + i15;
    const int diagW = qb >> 6;
    const int diagB = 2 * qB + 1;
    const int nt = diagB + 33;
    const int lo = (s * nt) / NS;
    const int hi = ((s + 1) * nt) / NS;

    bf16x8 qf[2];
    qf[0] = *(const bf16x8*)(Q + (size_t)qrow * D + h * 64 + g * 8);
    qf[1] = *(const bf16x8*)(Q + (size_t)qrow * D + h * 64 + 32 + g * 8);

    const short oneb = (short)0x3F80;
    const bf16x8 ones = {oneb, oneb, oneb, oneb, oneb, oneb, oneb, oneb};

    f32x4 o[4] = {};
    f32x4 ls = {};
    float m_run = -INFINITY;

    const int sr  = tid >> 3;
    const int scb = (tid & 7) * 16;
    const int ssw = scb ^ ((sr & 7) << 4);
    const char* kb0 = (const char*)Kb + ((size_t)sr * 1024 + h * 64) * 2 + scb;
    const char* vb0 = (const char*)Vt + ((size_t)(h * 64 + sr) * 4096) * 2 + scb;

    uint4 kreg, vreg;
    auto jt_of = [&](int t) { return (t <= diagB) ? t : (32 + (t - diagB - 1)); };
    auto stage = [&](int t) {
        const int jt = jt_of(t);
        kreg = *(const uint4*)(kb0 + (size_t)jt * 64 * 2048);
        vreg = *(const uint4*)(vb0 + (size_t)jt * 128);
    };
    auto wlds = [&](int buf) {
        *(uint4*)((char*)Ksm[buf] + sr * 128 + ssw) = kreg;
        *(uint4*)((char*)Vsm[buf] + sr * 128 + ssw) = vreg;
    };

    const int pbase = i15 * 128;
    const int psw = (i15 & 7) << 4;

    auto body = [&](int buf, int t) {
        const int jt = jt_of(t);
        f32x4 st[4];
        __builtin_amdgcn_s_setprio(1);
#pragma unroll
        for (int jg = 0; jg < 4; ++jg) {
            int jr = jg * 16 + i15;
            bf16x8 ka0 = *(const bf16x8*)((const char*)Ksm[buf] + jr * 128 +
                                          ((g * 16) ^ ((jr & 7) << 4)));
            bf16x8 ka1 = *(const bf16x8*)((const char*)Ksm[buf] + jr * 128 +
                                          ((64 + g * 16) ^ ((jr & 7) << 4)));
            f32x4 z = {};
            z = __builtin_amdgcn_mfma_f32_16x16x32_bf16(ka0, qf[0], z, 0, 0, 0);
            z = __builtin_amdgcn_mfma_f32_16x16x32_bf16(ka1, qf[1], z, 0, 0, 0);
            st[jg] = z;
        }
        __builtin_amdgcn_s_setprio(0);
        if (jt >= diagW && jt <= diagB) {
#pragma unroll
            for (int jg = 0; jg < 4; ++jg)
#pragma unroll
                for (int r = 0; r < 4; ++r) {
                    int j = jt * 64 + jg * 16 + 4 * g + r;
                    if (j > qrow) st[jg][r] = -50000.f;
                }
        }

        float a0 = fmaxf(fmaxf(st[0][0], st[0][1]), st[0][2]);
        float a1 = fmaxf(fmaxf(st[0][3], st[1][0]), st[1][1]);
        float a2 = fmaxf(fmaxf(st[1][2], st[1][3]), st[2][0]);
        float a3 = fmaxf(fmaxf(st[2][1], st[2][2]), st[2][3]);
        float a4 = fmaxf(fmaxf(st[3][0], st[3][1]), st[3][2]);
        float b0 = fmaxf(fmaxf(a0, a1), a2);
        float b1 = fmaxf(fmaxf(a3, a4), st[3][3]);
        float mt = fmaxf(b0, b1);
        mt = fmaxf(mt, __shfl_xor(mt, 16));
        mt = fmaxf(mt, __shfl_xor(mt, 32));

        const bool skip = __all(mt - m_run <= 8.f);
        float mnew, fscale;
        if (skip) { mnew = m_run; fscale = 1.f; }
        else      { mnew = fmaxf(m_run, mt); fscale = exp2f(m_run - mnew); }

        float pf[4][4];
#pragma unroll
        for (int jg = 0; jg < 4; ++jg)
#pragma unroll
            for (int r = 0; r < 4; ++r) pf[jg][r] = exp2f(st[jg][r] - mnew);
        m_run = mnew;

        if (!skip) {
#pragma unroll
            for (int r = 0; r < 4; ++r) {
                float fr = __shfl(fscale, 20 * g + r);
#pragma unroll
                for (int dg = 0; dg < 4; ++dg) o[dg][r] *= fr;
                ls[r] *= fr;
            }
        }

#pragma unroll
        for (int jg = 0; jg < 4; ++jg) {
            uint2 pk;
            pk.x = cvtpk(pf[jg][0], pf[jg][1]);
            pk.y = cvtpk(pf[jg][2], pf[jg][3]);
            *(uint2*)((char*)Psm[w] + pbase + ((jg * 32 + g * 8) ^ psw)) = pk;
        }

        __builtin_amdgcn_s_setprio(1);
#pragma unroll
        for (int jc = 0; jc < 2; ++jc) {
            bf16x8 pa = *(const bf16x8*)((const char*)Psm[w] + pbase +
                                         ((jc * 64 + g * 16) ^ psw));
            ls = __builtin_amdgcn_mfma_f32_16x16x32_bf16(pa, ones, ls, 0, 0, 0);
#pragma unroll
            for (int dg = 0; dg < 4; ++dg) {
                int dr = dg * 16 + i15;
                bf16x8 vb = *(const bf16x8*)((const char*)Vsm[buf] + dr * 128 +
                                             ((jc * 64 + g * 16) ^ ((dr & 7) << 4)));
                o[dg] = __builtin_amdgcn_mfma_f32_16x16x32_bf16(pa, vb, o[dg], 0, 0, 0);
            }
        }
        __builtin_amdgcn_s_setprio(0);
    };

    stage(lo);
    wlds(0);
    __syncthreads();

    int t = lo;
    for (; t + 1 < hi; t += 2) {
        stage(t + 1);
        body(0, t);
        wlds(1);
        __syncthreads();
        if (t + 2 < hi) stage(t + 2);
        body(1, t + 1);
        if (t + 2 < hi) { wlds(0); __syncthreads(); }
    }
    if (t < hi) body(0, t);

    if (NS > 1) {
#pragma unroll
        for (int r = 0; r < 4; ++r) {
            if (i15 == 4 * g + r) {
                float* mp = Ml + ((size_t)(s * 2048 + qrow) * 16 + h) * 2;
                mp[0] = m_run; mp[1] = ls[r];
            }
        }
#pragma unroll
        for (int r = 0; r < 4; ++r)
#pragma unroll
            for (int dg = 0; dg < 4; ++dg) {
                int row = qb + 4 * g + r;
                int col = h * 64 + dg * 16 + i15;
                Opart[(size_t)(s * 2048 + row) * 1024 + col] = f2bf(o[dg][r]);
            }
    } else {
#pragma unroll
        for (int r = 0; r < 4; ++r) {
            float inv = 1.f / ls[r];
#pragma unroll
            for (int dg = 0; dg < 4; ++dg) {
                int row = qb + 4 * g + r;
                int col = h * 64 + dg * 16 + i15;
                O[(size_t)row * D + col] = f2bf(o[dg][r] * inv);
            }
        }
    }
}

// ---------------------------------------------------------------------------
template <int NS>
__global__ __launch_bounds__(256) void attn_combine(
    const ushort* __restrict__ Opart, const float* __restrict__ Ml,
    ushort* __restrict__ O) {
    const int row = blockIdx.x, tid = threadIdx.x;
    const int c = tid * 4, h = c >> 6;
    float ms[NS], lsv[NS];
#pragma unroll
    for (int s = 0; s < NS; ++s) {
        const float* mp = Ml + ((size_t)(s * 2048 + row) * 16 + h) * 2;
        ms[s] = mp[0]; lsv[s] = mp[1];
    }
    float m = ms[0];
#pragma unroll
    for (int s = 1; s < NS; ++s) m = fmaxf(m, ms[s]);
    float denom = 0.f, wgt[NS];
#pragma unroll
    for (int s = 0; s < NS; ++s) { wgt[s] = exp2f(ms[s] - m); denom += lsv[s] * wgt[s]; }
    const float inv = 1.f / denom;
    float ax = 0, ay = 0, az = 0, aw = 0;
#pragma unroll
    for (int s = 0; s < NS; ++s) {
        ushort4 a = *(const ushort4*)(Opart + (size_t)(s * 2048 + row) * 1024 + c);
        ax += bf2f(a.x) * wgt[s]; ay += bf2f(a.y) * wgt[s];
        az += bf2f(a.z) * wgt[s]; aw += bf2f(a.w) * wgt[s];
    }
    ushort4 ob;
    ob.x = f2bf(ax * inv); ob.y = f2bf(ay * inv);
    ob.z = f2bf(az * inv); ob.w = f2bf(aw * inv);
    *(ushort4*)(O + (size_t)row * 1024 + c) = ob;
}

// ---------------------------------------------------------------------------
__global__ __launch_bounds__(256) void layernorm_k(
    const float* __restrict__ in, const float* __restrict__ gam,
    const float* __restrict__ bet, float* __restrict__ outf,
    ushort* __restrict__ outb) {
    const int row = blockIdx.x, tid = threadIdx.x;
    const float4 v = *(const float4*)(in + (size_t)row * 1024 + tid * 4);
    float s = v.x + v.y + v.z + v.w;
    float sq = v.x * v.x + v.y * v.y + v.z * v.z + v.w * v.w;
#pragma unroll
    for (int d = 1; d < 64; d <<= 1) {
        s += __shfl_xor(s, d);
        sq += __shfl_xor(sq, d);
    }
    __shared__ float red[8];
    const int w = tid >> 6;
    if ((tid & 63) == 0) { red[w] = s; red[4 + w] = sq; }
    __syncthreads();
    s = red[0] + red[1] + red[2] + red[3];
    sq = red[4] + red[5] + red[6] + red[7];
    const float mu = s * (1.f / 1024.f);
    const float rs = rsqrtf(sq * (1.f / 1024.f) - mu * mu + 1e-5f);
    const float4 gg = *(const float4*)(gam + tid * 4);
    const float4 bb = *(const float4*)(bet + tid * 4);
    float4 o;
    o.x = (v.x - mu) * rs * gg.x + bb.x;
    o.y = (v.y - mu) * rs * gg.y + bb.y;
    o.z = (v.z - mu) * rs * gg.z + bb.z;
    o.w = (v.w - mu) * rs * gg.w + bb.w;
    *(float4*)(outf + (size_t)row * 1024 + tid * 4) = o;
    if (outb) {
        ushort4 ob;
        ob.x = f2bf(o.x); ob.y = f2bf(o.y); ob.z = f2bf(o.z); ob.w = f2bf(o.w);
        *(ushort4*)(outb + (size_t)row * 1024 + tid * 4) = ob;
    }
}

// ---------------------------------------------------------------------------
// LN over (sum of NP split-K partials + bias + resid); partials f32 or bf16.
// ---------------------------------------------------------------------------
template <int NP, int PBF16, int OUTB>
__global__ __launch_bounds__(256) void layernorm_comb(
    const void* __restrict__ P,
    const float* __restrict__ bias, const float* __restrict__ resid,
    const float* __restrict__ gam, const float* __restrict__ bet,
    float* __restrict__ outf, ushort* __restrict__ outb) {
    const int row = blockIdx.x, tid = threadIdx.x;
    const float4 rr = *(const float4*)(resid + (size_t)row * 1024 + tid * 4);
    const float4 bs = *(const float4*)(bias + tid * 4);
    float4 v;
    v.x = rr.x + bs.x; v.y = rr.y + bs.y; v.z = rr.z + bs.z; v.w = rr.w + bs.w;
#pragma unroll
    for (int p = 0; p < NP; ++p) {
        if (PBF16) {
            ushort4 a = *(const ushort4*)((const ushort*)P +
                          (size_t)(p * 2048 + row) * 1024 + tid * 4);
            v.x += bf2f(a.x); v.y += bf2f(a.y); v.z += bf2f(a.z); v.w += bf2f(a.w);
        } else {
            float4 a = *(const float4*)((const float*)P +
                          (size_t)(p * 2048 + row) * 1024 + tid * 4);
            v.x += a.x; v.y += a.y; v.z += a.z; v.w += a.w;
        }
    }
    float s = v.x + v.y + v.z + v.w;
    float sq = v.x * v.x + v.y * v.y + v.z * v.z + v.w * v.w;
#pragma unroll
    for (int d = 1; d < 64; d <<= 1) {
        s += __shfl_xor(s, d);
        sq += __shfl_xor(sq, d);
    }
    __shared__ float red[8];
    const int w = tid >> 6;
    if ((tid & 63) == 0) { red[w] = s; red[4 + w] = sq; }
    __syncthreads();
    s = red[0] + red[1] + red[2] + red[3];
    sq = red[4] + red[5] + red[6] + red[7];
    const float mu = s * (1.f / 1024.f);
    const float rs = rsqrtf(sq * (1.f / 1024.f) - mu * mu + 1e-5f);
    const float4 gg = *(const float4*)(gam + tid * 4);
    const float4 bb = *(const float4*)(bet + tid * 4);
    float4 o;
    o.x = (v.x - mu) * rs * gg.x + bb.x;
    o.y = (v.y - mu) * rs * gg.y + bb.y;
    o.z = (v.z - mu) * rs * gg.z + bb.z;
    o.w = (v.w - mu) * rs * gg.w + bb.w;
    *(float4*)(outf + (size_t)row * 1024 + tid * 4) = o;
    if (OUTB) {
        ushort4 ob;
        ob.x = f2bf(o.x); ob.y = f2bf(o.y); ob.z = f2bf(o.z); ob.w = f2bf(o.w);
        *(ushort4*)(outb + (size_t)row * 1024 + tid * 4) = ob;
    }
}

// ---------------------------------------------------------------------------
extern "C" void kernel_launch(void* const* d_in, const int* in_sizes, int n_in,
                              void* d_out, int out_size, void* d_ws, size_t ws_size,
                              hipStream_t stream) {
    const float* x    = (const float*)d_in[0];
    const float* ctx  = (const float*)d_in[1];
    const float* Wq   = (const float*)d_in[2];
    const float* bq   = (const float*)d_in[3];
    const float* Wkv  = (const float*)d_in[4];
    const float* bkv  = (const float*)d_in[5];
    const float* Wo   = (const float*)d_in[6];
    const float* bo   = (const float*)d_in[7];
    const float* g1   = (const float*)d_in[8];
    const float* b1   = (const float*)d_in[9];
    const float* W1   = (const float*)d_in[10];
    const float* bf1  = (const float*)d_in[11];
    const float* W2   = (const float*)d_in[12];
    const float* bf2  = (const float*)d_in[13];
    const float* g2   = (const float*)d_in[14];
    const float* b2   = (const float*)d_in[15];

    char* ws = (char*)d_ws;
    const size_t MB = 1u << 20;
    ushort* XCb  = (ushort*)(ws + 0);        // 8MB; dead after QKV gemm
    ushort* WoT  = (ushort*)(ws + 8 * MB);   // 2MB
    ushort* W1T  = (ushort*)(ws + 10 * MB);  // 8MB
    ushort* W2T  = (ushort*)(ws + 18 * MB);  // 8MB
    ushort* WqT  = (ushort*)(ws + 26 * MB);  // 2MB; contiguous with WkvT
    ushort* WkvT = (ushort*)(ws + 28 * MB);  // 4MB; WqT+WkvT = WqkvT [3072][1024]
    ushort* Qs   = (ushort*)(ws + 32 * MB);  // 4MB; later x1f
    ushort* attn = (ushort*)(ws + 36 * MB);  // 4MB
    ushort* Kb   = (ushort*)(ws + 40 * MB);  // 8MB; later ffb (part)
    ushort* Vt   = (ushort*)(ws + 48 * MB);  // 8MB; later ffb (part)
    ushort* x1b  = (ushort*)(ws + 26 * MB);  // 4MB (over WqT+WkvT after use)
    float*  x1f  = (float*)(ws + 32 * MB);   // 8MB (over Qs+attn after use)
    ushort* ffb  = (ushort*)(ws + 40 * MB);  // 16MB (over Kb+Vt)
    float*  y1   = (float*)(ws + 56 * MB);   // 8MB (fallback path)
    ushort* Opart = (ushort*)(ws + 64 * MB); // 16MB bf16 attn partials (NS=4)
    ushort* Pwob  = (ushort*)(ws + 64 * MB); // 8MB Wo split-2 bf16 partials
    ushort* Pk4b  = (ushort*)(ws + 64 * MB); // 16MB FFN2 split-4 bf16 partials
    float*  Pk2   = (float*)(ws + 0);        // 16MB FFN2 split-2 fallback
    float*  Ml    = (float*)(ws + 80 * MB);  // 1MB

    prep_all<<<16384, 256, 0, stream>>>(x, ctx, XCb, Wq, Wkv, Wo, W1, W2,
                                        WqT, WkvT, WoT, W1T, W2T);
    // Fused QKV projection (WqT|WkvT contiguous = WqkvT [3072][1024])
    gemm_qkv<<<640, 256, 0, stream>>>(XCb, WqT, bq, bkv, Qs, Kb, Vt,
                                      0.18033688011112042f);

    const bool big = ws_size >= 82 * MB;
    if (big) {
        flash_attn<4><<<1024, 512, 0, stream>>>(Qs, Kb, Vt, nullptr, Opart, Ml);
        attn_combine<4><<<2048, 256, 0, stream>>>(Opart, Ml, attn);
        // Wo split-K x2 -> bf16 partials; combine + residual fused into LN1
        gemm_bt<64, 128, 0, 0, 0, 0, 1><<<dim3(8, 32, 2), 256, 0, stream>>>(
            attn, 1024, WoT, 1024, nullptr, nullptr, Pwob,
            2048, 1024, 512, 1.f);
        layernorm_comb<2, 1, 1><<<2048, 256, 0, stream>>>(
            Pwob, bo, x, g1, b1, x1f, x1b);
        gemm_bt<128, 128, 1, 0, 0, 0, 0><<<dim3(32, 16), 256, 0, stream>>>(
            x1b, 1024, W1T, 1024, bf1, nullptr, ffb,
            2048, 4096, 1024, 1.f);
        // FFN2 split-K x4, bf16 partials, merged in final LN
        gemm_bt<128, 128, 0, 0, 0, 0, 1><<<dim3(8, 16, 4), 256, 0, stream>>>(
            ffb, 4096, W2T, 4096, nullptr, nullptr, Pk4b,
            2048, 1024, 1024, 1.f);
        layernorm_comb<4, 1, 0><<<2048, 256, 0, stream>>>(
            Pk4b, bf2, x1f, g2, b2, (float*)d_out, nullptr);
    } else {
        flash_attn<1><<<256, 512, 0, stream>>>(Qs, Kb, Vt, attn, nullptr, nullptr);
        gemm_bt<64, 128, 0, 1, 1, 0, 0><<<dim3(8, 32), 256, 0, stream>>>(
            attn, 1024, WoT, 1024, bo, x, y1, 2048, 1024, 1024, 1.f);
        layernorm_k<<<2048, 256, 0, stream>>>(y1, g1, b1, x1f, x1b);
        gemm_bt<128, 128, 1, 0, 0, 0, 0><<<dim3(32, 16), 256, 0, stream>>>(
            x1b, 1024, W1T, 1024, bf1, nullptr, ffb, 2048, 4096, 1024, 1.f);
        gemm_bt<128, 128, 0, 1, 0, 0, 1><<<dim3(8, 16, 2), 256, 0, stream>>>(
            ffb, 4096, W2T, 4096, nullptr, nullptr, Pk2, 2048, 1024, 2048, 1.f);
        layernorm_comb<2, 0, 0><<<2048, 256, 0, stream>>>(
            Pk2, bf2, x1f, g2, b2, (float*)d_out, nullptr);
    }
}

// Round 15
// 204.823 us; speedup vs baseline: 1.0104x; 1.0058x over previous
//
#include <hip/hip_runtime.h>

// ---------------------------------------------------------------------------
// TransformerDecoderBlockV2: bf16 MFMA implementation for gfx950
// B=1, N=2048, M=2048, D=1024, H=16, dh=64, DFF=4096
// ---------------------------------------------------------------------------

using bf16x8 = __attribute__((ext_vector_type(8))) short;
using f32x4  = __attribute__((ext_vector_type(4))) float;

__device__ __forceinline__ ushort f2bf(float f) {
    unsigned u = __float_as_uint(f);
    unsigned r = (u + 0x7fffu + ((u >> 16) & 1u)) >> 16;
    return (ushort)r;
}

__device__ __forceinline__ float bf2f(ushort u) {
    return __uint_as_float((uint)u << 16);
}

__device__ __forceinline__ void gload16(const void* g, void* l) {
    __builtin_amdgcn_global_load_lds(
        (const __attribute__((address_space(1))) void*)g,
        (__attribute__((address_space(3))) void*)l, 16, 0, 0);
}

__device__ __forceinline__ float gelu_erf(float v) {
    return 0.5f * v * (1.0f + erff(v * 0.70710678118654752f));
}

__device__ __forceinline__ uint cvtpk(float a, float b) {
    uint r;
    asm("v_cvt_pk_bf16_f32 %0, %1, %2" : "=v"(r) : "v"(a), "v"(b));
    return r;
}

// ---------------------------------------------------------------------------
// Fused prep: blocks 0..4095 convert x/ctx; 4096..16383 transpose+cvt the 5
// weights. Transpose path vectorized: float4 loads, cvt_pk + uint2 stores.
// ---------------------------------------------------------------------------
__global__ __launch_bounds__(256) void prep_all(
    const float* __restrict__ x, const float* __restrict__ ctx,
    ushort* __restrict__ XCb,
    const float* __restrict__ Wq, const float* __restrict__ Wkv,
    const float* __restrict__ Wo, const float* __restrict__ W1,
    const float* __restrict__ W2,
    ushort* __restrict__ WqT, ushort* __restrict__ WkvT,
    ushort* __restrict__ WoT, ushort* __restrict__ W1T,
    ushort* __restrict__ W2T) {
    __shared__ float tile[32][33];
    int b = blockIdx.x;
    const int t = threadIdx.x;
    if (b < 4096) {
        const float* in = (b < 2048) ? x : ctx;
        ushort* out = XCb + ((b < 2048) ? 0 : (size_t)2048 * 1024);
        const int i = ((b & 2047) * 256 + t) * 4;
        float4 v = *(const float4*)(in + i);
        ushort4 o;
        o.x = f2bf(v.x); o.y = f2bf(v.y); o.z = f2bf(v.z); o.w = f2bf(v.w);
        *(ushort4*)(out + i) = o;
        return;
    }
    b -= 4096;
    const float* in; ushort* out; int R, C, loc;
    if (b < 1024)      { in = Wq;  out = WqT;  R = 1024; C = 1024; loc = b; }
    else if (b < 3072) { in = Wkv; out = WkvT; R = 1024; C = 2048; loc = b - 1024; }
    else if (b < 4096) { in = Wo;  out = WoT;  R = 1024; C = 1024; loc = b - 3072; }
    else if (b < 8192) { in = W1;  out = W1T;  R = 1024; C = 4096; loc = b - 4096; }
    else               { in = W2;  out = W2T;  R = 4096; C = 1024; loc = b - 8192; }
    const int nbx = C >> 5;
    const int c0 = (loc % nbx) * 32, r0 = (loc / nbx) * 32;
    {
        const int r = t >> 3, c4 = (t & 7) * 4;
        float4 v = *(const float4*)(in + (size_t)(r0 + r) * C + c0 + c4);
        tile[r][c4] = v.x; tile[r][c4 + 1] = v.y;
        tile[r][c4 + 2] = v.z; tile[r][c4 + 3] = v.w;
    }
    __syncthreads();
    {
        const int c = t >> 3, r4 = (t & 7) * 4;
        uint2 pk;
        pk.x = cvtpk(tile[r4][c], tile[r4 + 1][c]);
        pk.y = cvtpk(tile[r4 + 2][c], tile[r4 + 3][c]);
        *(uint2*)(out + (size_t)(c0 + c) * R + r0 + r4) = pk;
    }
}

// ---------------------------------------------------------------------------
// GEMM: C[M][N] = epilogue( A[M][K] * Bt[N][K]^T + bias ), bf16 in.
// 128x128 m97-class; SPLITK via blockIdx.z (f32 or bf16 partials).
// ---------------------------------------------------------------------------
template <int BM, int BN, int ACT, int OUTF32, int RES, int SCALED, int SPLITK>
__global__ __launch_bounds__(256) void gemm_bt(
    const ushort* __restrict__ A, int lda, const ushort* __restrict__ Bt, int ldb,
    const float* __restrict__ bias, const float* __restrict__ resid,
    void* __restrict__ Cout, int M, int N, int K, float scale) {
    constexpr int MR = BM / 32, NR = BN / 32;
    __shared__ __align__(16) ushort Asm[BM * 64];
    __shared__ __align__(16) ushort Bsm[BN * 64];
    const int tid = threadIdx.x;
    const int w = tid >> 6, lane = tid & 63, g = lane >> 4, i15 = lane & 15;
    const int wm = w >> 1, wn = w & 1;
    const int m0 = blockIdx.y * BM, n0 = blockIdx.x * BN;
    if (SPLITK) {
        A += (size_t)blockIdx.z * K;
        Bt += (size_t)blockIdx.z * K;
    }

    f32x4 acc[MR][NR] = {};

    for (int kt = 0; kt < K; kt += 64) {
#pragma unroll
        for (int q = 0; q < BM / 32; ++q) {
            int off = (w * (BM / 32) + q) * 1024 + lane * 16;
            int r = off >> 7, cb = off & 127;
            int scb = cb ^ ((r & 7) << 4);
            const void* src = (const char*)A + ((size_t)(m0 + r) * lda + kt) * 2 + scb;
            gload16(src, (char*)Asm + (w * (BM / 32) + q) * 1024);
        }
#pragma unroll
        for (int q = 0; q < BN / 32; ++q) {
            int off = (w * (BN / 32) + q) * 1024 + lane * 16;
            int r = off >> 7, cb = off & 127;
            int scb = cb ^ ((r & 7) << 4);
            const void* src = (const char*)Bt + ((size_t)(n0 + r) * ldb + kt) * 2 + scb;
            gload16(src, (char*)Bsm + (w * (BN / 32) + q) * 1024);
        }
        __syncthreads();

#pragma unroll
        for (int kc = 0; kc < 2; ++kc) {
            bf16x8 af[MR], bfr[NR];
#pragma unroll
            for (int mi = 0; mi < MR; ++mi) {
                int r = wm * (BM / 2) + mi * 16 + i15;
                af[mi] = *(const bf16x8*)((const char*)Asm + r * 128 +
                                          ((kc * 64 + g * 16) ^ ((r & 7) << 4)));
            }
#pragma unroll
            for (int ni = 0; ni < NR; ++ni) {
                int r = wn * (BN / 2) + ni * 16 + i15;
                bfr[ni] = *(const bf16x8*)((const char*)Bsm + r * 128 +
                                           ((kc * 64 + g * 16) ^ ((r & 7) << 4)));
            }
#pragma unroll
            for (int mi = 0; mi < MR; ++mi)
#pragma unroll
                for (int ni = 0; ni < NR; ++ni)
                    acc[mi][ni] = __builtin_amdgcn_mfma_f32_16x16x32_bf16(
                        af[mi], bfr[ni], acc[mi][ni], 0, 0, 0);
        }
        __syncthreads();
    }

    float* Cf = (float*)Cout;
    ushort* Cb = (ushort*)Cout;
    if (SPLITK) {
        Cf += (size_t)blockIdx.z * M * N;
        Cb += (size_t)blockIdx.z * M * N;
    }

#pragma unroll
    for (int ni = 0; ni < NR; ++ni) {
        int col = n0 + wn * (BN / 2) + ni * 16 + i15;
        float bb = bias ? bias[col] : 0.f;
#pragma unroll
        for (int mi = 0; mi < MR; ++mi) {
#pragma unroll
            for (int r2 = 0; r2 < 4; ++r2) {
                int row = m0 + wm * (BM / 2) + mi * 16 + 4 * g + r2;
                float v = acc[mi][ni][r2] + bb;
                if (ACT) v = gelu_erf(v);
                if (SCALED) v *= scale;
                size_t off = (size_t)row * N + col;
                if (OUTF32) {
                    float rv = RES ? resid[off] : 0.f;
                    Cf[off] = v + rv;
                } else {
                    Cb[off] = f2bf(v);
                }
            }
        }
    }
}

// ---------------------------------------------------------------------------
// Fused QKV projection over concatenated WqkvT [3072][1024].
// ---------------------------------------------------------------------------
__global__ __launch_bounds__(256) void gemm_qkv(
    const ushort* __restrict__ A,      // XCb [4096][1024]
    const ushort* __restrict__ Bt,     // WqkvT [3072][1024]
    const float* __restrict__ bq, const float* __restrict__ bkv,
    ushort* __restrict__ Qs, ushort* __restrict__ Kb, ushort* __restrict__ Vt,
    float qscale) {
    constexpr int MR = 4, NR = 4;
    __shared__ __align__(16) ushort Asm[128 * 64];
    __shared__ __align__(16) ushort Bsm[128 * 64];
    const int tid = threadIdx.x;
    const int w = tid >> 6, lane = tid & 63, g = lane >> 4, i15 = lane & 15;
    const int wm = w >> 1, wn = w & 1;
    const int bid = blockIdx.x;
    int bx, by;
    if (bid < 128) { bx = bid & 7; by = bid >> 3; }
    else { int b2 = bid - 128; bx = 8 + (b2 & 15); by = b2 >> 4; }
    const int m0 = by * 128, n0 = bx * 128;
    const int reg = (n0 < 1024) ? 0 : (n0 < 2048 ? 1 : 2);

    f32x4 acc[MR][NR] = {};

    for (int kt = 0; kt < 1024; kt += 64) {
#pragma unroll
        for (int q = 0; q < 4; ++q) {
            int off = (w * 4 + q) * 1024 + lane * 16;
            int r = off >> 7, cb = off & 127;
            int scb = cb ^ ((r & 7) << 4);
            const void* src = (const char*)A + ((size_t)(m0 + r) * 1024 + kt) * 2 + scb;
            gload16(src, (char*)Asm + (w * 4 + q) * 1024);
        }
#pragma unroll
        for (int q = 0; q < 4; ++q) {
            int off = (w * 4 + q) * 1024 + lane * 16;
            int r = off >> 7, cb = off & 127;
            int scb = cb ^ ((r & 7) << 4);
            const void* src = (const char*)Bt + ((size_t)(n0 + r) * 1024 + kt) * 2 + scb;
            gload16(src, (char*)Bsm + (w * 4 + q) * 1024);
        }
        __syncthreads();

#pragma unroll
        for (int kc = 0; kc < 2; ++kc) {
            bf16x8 af[MR], bfr[NR];
#pragma unroll
            for (int mi = 0; mi < MR; ++mi) {
                int r = wm * 64 + mi * 16 + i15;
                af[mi] = *(const bf16x8*)((const char*)Asm + r * 128 +
                                          ((kc * 64 + g * 16) ^ ((r & 7) << 4)));
            }
#pragma unroll
            for (int ni = 0; ni < NR; ++ni) {
                int r = wn * 64 + ni * 16 + i15;
                bfr[ni] = *(const bf16x8*)((const char*)Bsm + r * 128 +
                                           ((kc * 64 + g * 16) ^ ((r & 7) << 4)));
            }
#pragma unroll
            for (int mi = 0; mi < MR; ++mi)
#pragma unroll
                for (int ni = 0; ni < NR; ++ni)
                    acc[mi][ni] = __builtin_amdgcn_mfma_f32_16x16x32_bf16(
                        af[mi], bfr[ni], acc[mi][ni], 0, 0, 0);
        }
        __syncthreads();
    }

#pragma unroll
    for (int ni = 0; ni < NR; ++ni) {
        int col = n0 + wn * 64 + ni * 16 + i15;
        float bb = (reg == 0) ? bq[col] : bkv[col - 1024];
#pragma unroll
        for (int mi = 0; mi < MR; ++mi) {
            if (reg == 2) {
                int row = m0 + wm * 64 + mi * 16 + 4 * g;
                ushort4 ov;
                ov.x = f2bf(acc[mi][ni][0] + bb);
                ov.y = f2bf(acc[mi][ni][1] + bb);
                ov.z = f2bf(acc[mi][ni][2] + bb);
                ov.w = f2bf(acc[mi][ni][3] + bb);
                *(ushort4*)(Vt + (size_t)(col - 2048) * 4096 + row) = ov;
            } else {
#pragma unroll
                for (int r2 = 0; r2 < 4; ++r2) {
                    int row = m0 + wm * 64 + mi * 16 + 4 * g + r2;
                    float v = acc[mi][ni][r2] + bb;
                    if (reg == 0) {
                        Qs[(size_t)row * 1024 + col] = f2bf(v * qscale);
                    } else {
                        Kb[(size_t)row * 1024 + (col - 1024)] = f2bf(v);
                    }
                }
            }
        }
    }
}

// ---------------------------------------------------------------------------
// Flash attention v7b: 8 waves x 16 q-rows, reg-staged dbuf K/V LDS,
// 16x16 swapped QK^T, exp2, defer-max, setprio, bf16 split partials,
// l via MFMA ones-column trick.
// NS>1 grid = 256*NS blocks, bid = h + 16*s + 96*qB_idx (split interleaved,
// heavy qB first) -> tight residency packing (48KB LDS = 3 blocks/CU).
// ---------------------------------------------------------------------------
template <int NS>
__global__ __launch_bounds__(512) void flash_attn(
    const ushort* __restrict__ Q,    // [2048][1024] bf16 (pre-scaled 0.125*log2e)
    const ushort* __restrict__ Kb,   // [4096][1024] bf16
    const ushort* __restrict__ Vt,   // [1024][4096] bf16
    ushort* __restrict__ O,          // NS==1: [2048][1024] bf16
    ushort* __restrict__ Opart,      // NS>1: [NS][2048][1024] bf16 (unnormalized)
    float* __restrict__ Ml) {        // NS>1: [NS][2048][16][2] f32
    constexpr int D = 1024;
    __shared__ __align__(16) ushort Ksm[2][64 * 64];
    __shared__ __align__(16) ushort Vsm[2][64 * 64];
    __shared__ __align__(16) ushort Psm[8][16 * 64];

    const int tid = threadIdx.x;
    const int w = tid >> 6, lane = tid & 63, g = lane >> 4, i15 = lane & 15;
    const int bid = blockIdx.x;
    const int h = bid & 15;                 // bid%8 == h%8 -> same-head same-XCD
    const int rest = bid >> 4;
    const int s = (NS > 1) ? (rest % NS) : 0;
    const int qB = 15 - ((NS > 1) ? (rest / NS) : rest);   // heavy q-blocks first
    const int qb = qB * 128 + w * 16;
    const int qrow = qb + i15;
    const int diagW = qb >> 6;
    const int diagB = 2 * qB + 1;
    const int nt = diagB + 33;
    const int lo = (s * nt) / NS;
    const int hi = ((s + 1) * nt) / NS;

    bf16x8 qf[2];
    qf[0] = *(const bf16x8*)(Q + (size_t)qrow * D + h * 64 + g * 8);
    qf[1] = *(const bf16x8*)(Q + (size_t)qrow * D + h * 64 + 32 + g * 8);

    const short oneb = (short)0x3F80;
    const bf16x8 ones = {oneb, oneb, oneb, oneb, oneb, oneb, oneb, oneb};

    f32x4 o[4] = {};
    f32x4 ls = {};
    float m_run = -INFINITY;

    const int sr  = tid >> 3;
    const int scb = (tid & 7) * 16;
    const int ssw = scb ^ ((sr & 7) << 4);
    const char* kb0 = (const char*)Kb + ((size_t)sr * 1024 + h * 64) * 2 + scb;
    const char* vb0 = (const char*)Vt + ((size_t)(h * 64 + sr) * 4096) * 2 + scb;

    uint4 kreg, vreg;
    auto jt_of = [&](int t) { return (t <= diagB) ? t : (32 + (t - diagB - 1)); };
    auto stage = [&](int t) {
        const int jt = jt_of(t);
        kreg = *(const uint4*)(kb0 + (size_t)jt * 64 * 2048);
        vreg = *(const uint4*)(vb0 + (size_t)jt * 128);
    };
    auto wlds = [&](int buf) {
        *(uint4*)((char*)Ksm[buf] + sr * 128 + ssw) = kreg;
        *(uint4*)((char*)Vsm[buf] + sr * 128 + ssw) = vreg;
    };

    const int pbase = i15 * 128;
    const int psw = (i15 & 7) << 4;

    auto body = [&](int buf, int t) {
        const int jt = jt_of(t);
        f32x4 st[4];
        __builtin_amdgcn_s_setprio(1);
#pragma unroll
        for (int jg = 0; jg < 4; ++jg) {
            int jr = jg * 16 + i15;
            bf16x8 ka0 = *(const bf16x8*)((const char*)Ksm[buf] + jr * 128 +
                                          ((g * 16) ^ ((jr & 7) << 4)));
            bf16x8 ka1 = *(const bf16x8*)((const char*)Ksm[buf] + jr * 128 +
                                          ((64 + g * 16) ^ ((jr & 7) << 4)));
            f32x4 z = {};
            z = __builtin_amdgcn_mfma_f32_16x16x32_bf16(ka0, qf[0], z, 0, 0, 0);
            z = __builtin_amdgcn_mfma_f32_16x16x32_bf16(ka1, qf[1], z, 0, 0, 0);
            st[jg] = z;
        }
        __builtin_amdgcn_s_setprio(0);
        if (jt >= diagW && jt <= diagB) {
#pragma unroll
            for (int jg = 0; jg < 4; ++jg)
#pragma unroll
                for (int r = 0; r < 4; ++r) {
                    int j = jt * 64 + jg * 16 + 4 * g + r;
                    if (j > qrow) st[jg][r] = -50000.f;
                }
        }

        float a0 = fmaxf(fmaxf(st[0][0], st[0][1]), st[0][2]);
        float a1 = fmaxf(fmaxf(st[0][3], st[1][0]), st[1][1]);
        float a2 = fmaxf(fmaxf(st[1][2], st[1][3]), st[2][0]);
        float a3 = fmaxf(fmaxf(st[2][1], st[2][2]), st[2][3]);
        float a4 = fmaxf(fmaxf(st[3][0], st[3][1]), st[3][2]);
        float b0 = fmaxf(fmaxf(a0, a1), a2);
        float b1 = fmaxf(fmaxf(a3, a4), st[3][3]);
        float mt = fmaxf(b0, b1);
        mt = fmaxf(mt, __shfl_xor(mt, 16));
        mt = fmaxf(mt, __shfl_xor(mt, 32));

        const bool skip = __all(mt - m_run <= 8.f);
        float mnew, fscale;
        if (skip) { mnew = m_run; fscale = 1.f; }
        else      { mnew = fmaxf(m_run, mt); fscale = exp2f(m_run - mnew); }

        float pf[4][4];
#pragma unroll
        for (int jg = 0; jg < 4; ++jg)
#pragma unroll
            for (int r = 0; r < 4; ++r) pf[jg][r] = exp2f(st[jg][r] - mnew);
        m_run = mnew;

        if (!skip) {
#pragma unroll
            for (int r = 0; r < 4; ++r) {
                float fr = __shfl(fscale, 20 * g + r);
#pragma unroll
                for (int dg = 0; dg < 4; ++dg) o[dg][r] *= fr;
                ls[r] *= fr;
            }
        }

#pragma unroll
        for (int jg = 0; jg < 4; ++jg) {
            uint2 pk;
            pk.x = cvtpk(pf[jg][0], pf[jg][1]);
            pk.y = cvtpk(pf[jg][2], pf[jg][3]);
            *(uint2*)((char*)Psm[w] + pbase + ((jg * 32 + g * 8) ^ psw)) = pk;
        }

        __builtin_amdgcn_s_setprio(1);
#pragma unroll
        for (int jc = 0; jc < 2; ++jc) {
            bf16x8 pa = *(const bf16x8*)((const char*)Psm[w] + pbase +
                                         ((jc * 64 + g * 16) ^ psw));
            ls = __builtin_amdgcn_mfma_f32_16x16x32_bf16(pa, ones, ls, 0, 0, 0);
#pragma unroll
            for (int dg = 0; dg < 4; ++dg) {
                int dr = dg * 16 + i15;
                bf16x8 vb = *(const bf16x8*)((const char*)Vsm[buf] + dr * 128 +
                                             ((jc * 64 + g * 16) ^ ((dr & 7) << 4)));
                o[dg] = __builtin_amdgcn_mfma_f32_16x16x32_bf16(pa, vb, o[dg], 0, 0, 0);
            }
        }
        __builtin_amdgcn_s_setprio(0);
    };

    stage(lo);
    wlds(0);
    __syncthreads();

    int t = lo;
    for (; t + 1 < hi; t += 2) {
        stage(t + 1);
        body(0, t);
        wlds(1);
        __syncthreads();
        if (t + 2 < hi) stage(t + 2);
        body(1, t + 1);
        if (t + 2 < hi) { wlds(0); __syncthreads(); }
    }
    if (t < hi) body(0, t);

    if (NS > 1) {
#pragma unroll
        for (int r = 0; r < 4; ++r) {
            if (i15 == 4 * g + r) {
                float* mp = Ml + ((size_t)(s * 2048 + qrow) * 16 + h) * 2;
                mp[0] = m_run; mp[1] = ls[r];
            }
        }
#pragma unroll
        for (int r = 0; r < 4; ++r)
#pragma unroll
            for (int dg = 0; dg < 4; ++dg) {
                int row = qb + 4 * g + r;
                int col = h * 64 + dg * 16 + i15;
                Opart[(size_t)(s * 2048 + row) * 1024 + col] = f2bf(o[dg][r]);
            }
    } else {
#pragma unroll
        for (int r = 0; r < 4; ++r) {
            float inv = 1.f / ls[r];
#pragma unroll
            for (int dg = 0; dg < 4; ++dg) {
                int row = qb + 4 * g + r;
                int col = h * 64 + dg * 16 + i15;
                O[(size_t)row * D + col] = f2bf(o[dg][r] * inv);
            }
        }
    }
}

// ---------------------------------------------------------------------------
template <int NS>
__global__ __launch_bounds__(256) void attn_combine(
    const ushort* __restrict__ Opart, const float* __restrict__ Ml,
    ushort* __restrict__ O) {
    const int row = blockIdx.x, tid = threadIdx.x;
    const int c = tid * 4, h = c >> 6;
    float ms[NS], lsv[NS];
#pragma unroll
    for (int s = 0; s < NS; ++s) {
        const float* mp = Ml + ((size_t)(s * 2048 + row) * 16 + h) * 2;
        ms[s] = mp[0]; lsv[s] = mp[1];
    }
    float m = ms[0];
#pragma unroll
    for (int s = 1; s < NS; ++s) m = fmaxf(m, ms[s]);
    float denom = 0.f, wgt[NS];
#pragma unroll
    for (int s = 0; s < NS; ++s) { wgt[s] = exp2f(ms[s] - m); denom += lsv[s] * wgt[s]; }
    const float inv = 1.f / denom;
    float ax = 0, ay = 0, az = 0, aw = 0;
#pragma unroll
    for (int s = 0; s < NS; ++s) {
        ushort4 a = *(const ushort4*)(Opart + (size_t)(s * 2048 + row) * 1024 + c);
        ax += bf2f(a.x) * wgt[s]; ay += bf2f(a.y) * wgt[s];
        az += bf2f(a.z) * wgt[s]; aw += bf2f(a.w) * wgt[s];
    }
    ushort4 ob;
    ob.x = f2bf(ax * inv); ob.y = f2bf(ay * inv);
    ob.z = f2bf(az * inv); ob.w = f2bf(aw * inv);
    *(ushort4*)(O + (size_t)row * 1024 + c) = ob;
}

// ---------------------------------------------------------------------------
__global__ __launch_bounds__(256) void layernorm_k(
    const float* __restrict__ in, const float* __restrict__ gam,
    const float* __restrict__ bet, float* __restrict__ outf,
    ushort* __restrict__ outb) {
    const int row = blockIdx.x, tid = threadIdx.x;
    const float4 v = *(const float4*)(in + (size_t)row * 1024 + tid * 4);
    float s = v.x + v.y + v.z + v.w;
    float sq = v.x * v.x + v.y * v.y + v.z * v.z + v.w * v.w;
#pragma unroll
    for (int d = 1; d < 64; d <<= 1) {
        s += __shfl_xor(s, d);
        sq += __shfl_xor(sq, d);
    }
    __shared__ float red[8];
    const int w = tid >> 6;
    if ((tid & 63) == 0) { red[w] = s; red[4 + w] = sq; }
    __syncthreads();
    s = red[0] + red[1] + red[2] + red[3];
    sq = red[4] + red[5] + red[6] + red[7];
    const float mu = s * (1.f / 1024.f);
    const float rs = rsqrtf(sq * (1.f / 1024.f) - mu * mu + 1e-5f);
    const float4 gg = *(const float4*)(gam + tid * 4);
    const float4 bb = *(const float4*)(bet + tid * 4);
    float4 o;
    o.x = (v.x - mu) * rs * gg.x + bb.x;
    o.y = (v.y - mu) * rs * gg.y + bb.y;
    o.z = (v.z - mu) * rs * gg.z + bb.z;
    o.w = (v.w - mu) * rs * gg.w + bb.w;
    *(float4*)(outf + (size_t)row * 1024 + tid * 4) = o;
    if (outb) {
        ushort4 ob;
        ob.x = f2bf(o.x); ob.y = f2bf(o.y); ob.z = f2bf(o.z); ob.w = f2bf(o.w);
        *(ushort4*)(outb + (size_t)row * 1024 + tid * 4) = ob;
    }
}

// ---------------------------------------------------------------------------
// LN over (sum of NP split-K partials + bias + resid); partials f32 or bf16.
// ---------------------------------------------------------------------------
template <int NP, int PBF16, int OUTB>
__global__ __launch_bounds__(256) void layernorm_comb(
    const void* __restrict__ P,
    const float* __restrict__ bias, const float* __restrict__ resid,
    const float* __restrict__ gam, const float* __restrict__ bet,
    float* __restrict__ outf, ushort* __restrict__ outb) {
    const int row = blockIdx.x, tid = threadIdx.x;
    const float4 rr = *(const float4*)(resid + (size_t)row * 1024 + tid * 4);
    const float4 bs = *(const float4*)(bias + tid * 4);
    float4 v;
    v.x = rr.x + bs.x; v.y = rr.y + bs.y; v.z = rr.z + bs.z; v.w = rr.w + bs.w;
#pragma unroll
    for (int p = 0; p < NP; ++p) {
        if (PBF16) {
            ushort4 a = *(const ushort4*)((const ushort*)P +
                          (size_t)(p * 2048 + row) * 1024 + tid * 4);
            v.x += bf2f(a.x); v.y += bf2f(a.y); v.z += bf2f(a.z); v.w += bf2f(a.w);
        } else {
            float4 a = *(const float4*)((const float*)P +
                          (size_t)(p * 2048 + row) * 1024 + tid * 4);
            v.x += a.x; v.y += a.y; v.z += a.z; v.w += a.w;
        }
    }
    float s = v.x + v.y + v.z + v.w;
    float sq = v.x * v.x + v.y * v.y + v.z * v.z + v.w * v.w;
#pragma unroll
    for (int d = 1; d < 64; d <<= 1) {
        s += __shfl_xor(s, d);
        sq += __shfl_xor(sq, d);
    }
    __shared__ float red[8];
    const int w = tid >> 6;
    if ((tid & 63) == 0) { red[w] = s; red[4 + w] = sq; }
    __syncthreads();
    s = red[0] + red[1] + red[2] + red[3];
    sq = red[4] + red[5] + red[6] + red[7];
    const float mu = s * (1.f / 1024.f);
    const float rs = rsqrtf(sq * (1.f / 1024.f) - mu * mu + 1e-5f);
    const float4 gg = *(const float4*)(gam + tid * 4);
    const float4 bb = *(const float4*)(bet + tid * 4);
    float4 o;
    o.x = (v.x - mu) * rs * gg.x + bb.x;
    o.y = (v.y - mu) * rs * gg.y + bb.y;
    o.z = (v.z - mu) * rs * gg.z + bb.z;
    o.w = (v.w - mu) * rs * gg.w + bb.w;
    *(float4*)(outf + (size_t)row * 1024 + tid * 4) = o;
    if (OUTB) {
        ushort4 ob;
        ob.x = f2bf(o.x); ob.y = f2bf(o.y); ob.z = f2bf(o.z); ob.w = f2bf(o.w);
        *(ushort4*)(outb + (size_t)row * 1024 + tid * 4) = ob;
    }
}

// ---------------------------------------------------------------------------
extern "C" void kernel_launch(void* const* d_in, const int* in_sizes, int n_in,
                              void* d_out, int out_size, void* d_ws, size_t ws_size,
                              hipStream_t stream) {
    const float* x    = (const float*)d_in[0];
    const float* ctx  = (const float*)d_in[1];
    const float* Wq   = (const float*)d_in[2];
    const float* bq   = (const float*)d_in[3];
    const float* Wkv  = (const float*)d_in[4];
    const float* bkv  = (const float*)d_in[5];
    const float* Wo   = (const float*)d_in[6];
    const float* bo   = (const float*)d_in[7];
    const float* g1   = (const float*)d_in[8];
    const float* b1   = (const float*)d_in[9];
    const float* W1   = (const float*)d_in[10];
    const float* bf1  = (const float*)d_in[11];
    const float* W2   = (const float*)d_in[12];
    const float* bf2  = (const float*)d_in[13];
    const float* g2   = (const float*)d_in[14];
    const float* b2   = (const float*)d_in[15];

    char* ws = (char*)d_ws;
    const size_t MB = 1u << 20;
    ushort* XCb  = (ushort*)(ws + 0);        // 8MB; dead after QKV gemm
    ushort* WoT  = (ushort*)(ws + 8 * MB);   // 2MB
    ushort* W1T  = (ushort*)(ws + 10 * MB);  // 8MB
    ushort* W2T  = (ushort*)(ws + 18 * MB);  // 8MB
    ushort* WqT  = (ushort*)(ws + 26 * MB);  // 2MB; contiguous with WkvT
    ushort* WkvT = (ushort*)(ws + 28 * MB);  // 4MB; WqT+WkvT = WqkvT [3072][1024]
    ushort* Qs   = (ushort*)(ws + 32 * MB);  // 4MB; later x1f
    ushort* attn = (ushort*)(ws + 36 * MB);  // 4MB
    ushort* Kb   = (ushort*)(ws + 40 * MB);  // 8MB; later ffb (part)
    ushort* Vt   = (ushort*)(ws + 48 * MB);  // 8MB; later ffb (part)
    ushort* x1b  = (ushort*)(ws + 26 * MB);  // 4MB (over WqT+WkvT after use)
    float*  x1f  = (float*)(ws + 32 * MB);   // 8MB (over Qs+attn after use)
    ushort* ffb  = (ushort*)(ws + 40 * MB);  // 16MB (over Kb+Vt)
    float*  y1   = (float*)(ws + 56 * MB);   // 8MB (fallback path)
    ushort* Opart = (ushort*)(ws + 64 * MB); // NS*4MB bf16 attn partials
    ushort* Pwob  = (ushort*)(ws + 64 * MB); // 8MB Wo split-2 bf16 partials
    ushort* Pk4b  = (ushort*)(ws + 64 * MB); // 16MB FFN2 split-4 bf16 partials
    float*  Pk2   = (float*)(ws + 0);        // 16MB FFN2 split-2 fallback
    float*  Ml6   = (float*)(ws + 88 * MB);  // 1.5MB (NS=6)
    float*  Ml4   = (float*)(ws + 80 * MB);  // 1MB   (NS=4)

    prep_all<<<16384, 256, 0, stream>>>(x, ctx, XCb, Wq, Wkv, Wo, W1, W2,
                                        WqT, WkvT, WoT, W1T, W2T);
    // Fused QKV projection (WqT|WkvT contiguous = WqkvT [3072][1024])
    gemm_qkv<<<640, 256, 0, stream>>>(XCb, WqT, bq, bkv, Qs, Kb, Vt,
                                      0.18033688011112042f);

    if (ws_size >= 90 * MB) {
        // NS=6: 1536 blocks = exactly 2 residency rounds at 3 blocks/CU
        flash_attn<6><<<1536, 512, 0, stream>>>(Qs, Kb, Vt, nullptr, Opart, Ml6);
        attn_combine<6><<<2048, 256, 0, stream>>>(Opart, Ml6, attn);
    } else if (ws_size >= 82 * MB) {
        flash_attn<4><<<1024, 512, 0, stream>>>(Qs, Kb, Vt, nullptr, Opart, Ml4);
        attn_combine<4><<<2048, 256, 0, stream>>>(Opart, Ml4, attn);
    } else {
        flash_attn<1><<<256, 512, 0, stream>>>(Qs, Kb, Vt, attn, nullptr, nullptr);
    }

    if (ws_size >= 82 * MB) {
        // Wo split-K x2 -> bf16 partials; combine + residual fused into LN1
        gemm_bt<64, 128, 0, 0, 0, 0, 1><<<dim3(8, 32, 2), 256, 0, stream>>>(
            attn, 1024, WoT, 1024, nullptr, nullptr, Pwob,
            2048, 1024, 512, 1.f);
        layernorm_comb<2, 1, 1><<<2048, 256, 0, stream>>>(
            Pwob, bo, x, g1, b1, x1f, x1b);
        gemm_bt<128, 128, 1, 0, 0, 0, 0><<<dim3(32, 16), 256, 0, stream>>>(
            x1b, 1024, W1T, 1024, bf1, nullptr, ffb,
            2048, 4096, 1024, 1.f);
        // FFN2 split-K x4, bf16 partials, merged in final LN
        gemm_bt<128, 128, 0, 0, 0, 0, 1><<<dim3(8, 16, 4), 256, 0, stream>>>(
            ffb, 4096, W2T, 4096, nullptr, nullptr, Pk4b,
            2048, 1024, 1024, 1.f);
        layernorm_comb<4, 1, 0><<<2048, 256, 0, stream>>>(
            Pk4b, bf2, x1f, g2, b2, (float*)d_out, nullptr);
    } else {
        gemm_bt<64, 128, 0, 1, 1, 0, 0><<<dim3(8, 32), 256, 0, stream>>>(
            attn, 1024, WoT, 1024, bo, x, y1, 2048, 1024, 1024, 1.f);
        layernorm_k<<<2048, 256, 0, stream>>>(y1, g1, b1, x1f, x1b);
        gemm_bt<128, 128, 1, 0, 0, 0, 0><<<dim3(32, 16), 256, 0, stream>>>(
            x1b, 1024, W1T, 1024, bf1, nullptr, ffb, 2048, 4096, 1024, 1.f);
        gemm_bt<128, 128, 0, 1, 0, 0, 1><<<dim3(8, 16, 2), 256, 0, stream>>>(
            ffb, 4096, W2T, 4096, nullptr, nullptr, Pk2, 2048, 1024, 2048, 1.f);
        layernorm_comb<2, 0, 0><<<2048, 256, 0, stream>>>(
            Pk2, bf2, x1f, g2, b2, (float*)d_out, nullptr);
    }
}